// Round 4
// baseline (580.429 us; speedup 1.0000x reference)
//
#include <hip/hip_runtime.h>
#include <cstring>
#include <cmath>
#include <cstdint>

#define N_TOK 65536
#define DIN 128
#define HD 64
#define TN 12
#define ON 3
#define NHOPS 4
#define TPB 256
#define TPB_HOP 512      // 8 waves: 8 feature-stripes x 64 tokens
#define TOKB 64          // tokens per k_hop block (8 threads/token)
#define NCAT 13

struct HopConst {
  float w[TN][ON];     // softmax mixture weights per temper
  unsigned ck0, ck1;   // categorical key for this hop
  int last_hop;
};

// ---- threefry2x32 (exact JAX semantics) ----
__host__ __device__ __forceinline__ void tf2x32(unsigned k0, unsigned k1,
                                                unsigned x0, unsigned x1,
                                                unsigned& o0, unsigned& o1) {
  unsigned ks2 = k0 ^ k1 ^ 0x1BD11BDAu;
  x0 += k0; x1 += k1;
#define TFR(r) { x0 += x1; x1 = (x1 << (r)) | (x1 >> (32 - (r))); x1 ^= x0; }
  TFR(13) TFR(15) TFR(26) TFR(6)
  x0 += k1;  x1 += ks2 + 1u;
  TFR(17) TFR(29) TFR(16) TFR(24)
  x0 += ks2; x1 += k0 + 2u;
  TFR(13) TFR(15) TFR(26) TFR(6)
  x0 += k0;  x1 += k1 + 3u;
  TFR(17) TFR(29) TFR(16) TFR(24)
  x0 += k1;  x1 += ks2 + 4u;
  TFR(13) TFR(15) TFR(26) TFR(6)
  x0 += ks2; x1 += k0 + 5u;
#undef TFR
  o0 = x0; o1 = x1;
}

// partitionable-mode 32-bit random bits, element j: o0^o1 of tf(key, 0, j)
__host__ __device__ __forceinline__ unsigned tf_bits32(unsigned k0, unsigned k1, unsigned j) {
  unsigned o0, o1;
  tf2x32(k0, k1, 0u, j, o0, o1);
  return o0 ^ o1;
}

// ---- kernels ----

// proj: states = x @ proj_W + proj_b; init tempers/done; histogram cnt0
__global__ __launch_bounds__(TPB, 2) void k_init(
    const float* __restrict__ x, const float* __restrict__ pW,
    const float* __restrict__ pb, const int* __restrict__ itemp,
    float* __restrict__ states, int* __restrict__ tempers,
    int* __restrict__ done, int* __restrict__ cnt0)
{
  __shared__ int lcnt[TN];
  const int tid = threadIdx.x;
  if (tid < TN) lcnt[tid] = 0;
  __syncthreads();
  const int n = blockIdx.x * TPB + tid;
  float acc[HD];
  #pragma unroll
  for (int k = 0; k < HD; ++k) acc[k] = pb[k];
  const float* xrow = x + (size_t)n * DIN;
  for (int d4 = 0; d4 < DIN / 4; ++d4) {
    const float4 xv = *(const float4*)(xrow + d4 * 4);
    const float xs[4] = {xv.x, xv.y, xv.z, xv.w};
    #pragma unroll
    for (int dd = 0; dd < 4; ++dd) {
      const float* wr = pW + (d4 * 4 + dd) * HD;   // wave-uniform -> s_load
      #pragma unroll
      for (int k = 0; k < HD; ++k) acc[k] = fmaf(xs[dd], wr[k], acc[k]);
    }
  }
  float* srow = states + (size_t)n * HD;
  #pragma unroll
  for (int k4 = 0; k4 < HD / 4; ++k4) {
    float4 v; v.x = acc[k4*4]; v.y = acc[k4*4+1]; v.z = acc[k4*4+2]; v.w = acc[k4*4+3];
    *(float4*)(srow + k4 * 4) = v;
  }
  const int t = itemp[n];
  tempers[n] = t;
  done[n] = 0;
  atomicAdd(&lcnt[t], 1);
  __syncthreads();
  if (tid < TN && lcnt[tid] > 0) atomicAdd(&cnt0[tid], lcnt[tid]);
}

// one-time weight transposes into ws (feature-major stripes for scalar streaming)
__global__ __launch_bounds__(TPB) void k_tr(
    const float* __restrict__ W1, const float* __restrict__ W2,
    const float* __restrict__ rW1, const float* __restrict__ rW2,
    float* __restrict__ W1T, float* __restrict__ W2T,
    float* __restrict__ rW1T, float* __restrict__ rW2T)
{
  const int i = blockIdx.x * TPB + threadIdx.x;
  if (i < TN * ON * HD * HD) {
    const int m = i >> 12, h = (i >> 6) & 63, j = i & 63;   // in: [m][h][j]
    W1T[(m << 12) + (j << 6) + h] = W1[i];                  // out: [m][j][h]
    W2T[(m << 12) + (j << 6) + h] = W2[i];
  }
  if (i < HD * HD) {
    const int h = i >> 6, j = i & 63;
    rW1T[(j << 6) + h] = rW1[i];
  }
  if (i < NCAT * HD) {
    const int c = i >> 6, h = i & 63;
    rW2T[i] = rW2[h * NCAT + c];                            // rW2T[c][h]
  }
}

// 64-padded prefix offsets over temper counts
__global__ void k_prefix(const int* __restrict__ cnt, int* __restrict__ offp) {
  if (threadIdx.x == 0 && blockIdx.x == 0) {
    int o = 0;
    for (int t = 0; t < TN; ++t) { offp[t] = o; o += (cnt[t] + TOKB - 1) & ~(TOKB - 1); }
    offp[TN] = o;
  }
}

// scatter active tokens into per-temper compact regions
__global__ __launch_bounds__(TPB) void k_scatter(
    const int* __restrict__ tempers, const int* __restrict__ done,
    const int* __restrict__ offp, int* __restrict__ cursor, int* __restrict__ compact)
{
  __shared__ int lcnt[TN], lbase[TN];
  const int tid = threadIdx.x;
  if (tid < TN) lcnt[tid] = 0;
  __syncthreads();
  const int n = blockIdx.x * TPB + tid;
  int t = -1, lpos = 0;
  if (!done[n]) { t = tempers[n]; lpos = atomicAdd(&lcnt[t], 1); }
  __syncthreads();
  if (tid < TN && lcnt[tid] > 0) lbase[tid] = atomicAdd(&cursor[tid], lcnt[tid]);
  __syncthreads();
  if (t >= 0) compact[offp[t] + lbase[t] + lpos] = n;
}

// main per-hop kernel: 8 threads per token (8 features each), transposed
// scalar weight stripes; 8 waves/block -> 32 waves/CU for latency hiding.
__global__ __launch_bounds__(TPB_HOP, 8) void k_hop(
    float* __restrict__ states, int* __restrict__ tempers, int* __restrict__ done,
    const int* __restrict__ compact, const int* __restrict__ cnt,
    const int* __restrict__ offp,
    const float* __restrict__ W1T, const float* __restrict__ b1,
    const float* __restrict__ W2T, const float* __restrict__ b2,
    const float* __restrict__ rW1T, const float* __restrict__ rb1,
    const float* __restrict__ rW2T, const float* __restrict__ rb2,
    int* __restrict__ cnt_next, HopConst hc)
{
  __shared__ float xch[HD][TOKB];     // [feature][token-slot], 2-way (free) banks
  __shared__ int lcnt[TN];
  const int tid = threadIdx.x;
  const int tokloc = tid & 63;
  const int fg = __builtin_amdgcn_readfirstlane(tid >> 6);  // wave-uniform stripe id
  const int fbase = fg * 8;
  const int bstart = blockIdx.x * TOKB;
  if (bstart >= offp[TN]) return;
  int tt = 0;
  #pragma unroll
  for (int i = 1; i < TN; ++i) if (bstart >= offp[i]) tt = i;
  const int t = __builtin_amdgcn_readfirstlane(tt);
  const int cntt = cnt[t];
  const bool act = (bstart + tokloc - offp[t]) < cntt;
  const int token = compact[act ? (bstart + tokloc) : offp[t]];
  const float* __restrict__ srow = states + (size_t)token * HD;

  float out[8];
  #pragma unroll
  for (int j = 0; j < 8; ++j) out[j] = 0.0f;

  #pragma unroll 1
  for (int o = 0; o < ON; ++o) {
    const size_t mb = ((size_t)(t * ON + o)) << 12;
    const float* __restrict__ W1o = W1T + mb;             // [j][h] stripes
    const float* __restrict__ b1o = b1 + (t * ON + o) * HD;
    float acc[8];
    #pragma unroll
    for (int j = 0; j < 8; ++j) acc[j] = b1o[fbase + j];
    for (int h4 = 0; h4 < HD / 4; ++h4) {
      const float4 sv = *(const float4*)(srow + h4 * 4);
      const float ss[4] = {sv.x, sv.y, sv.z, sv.w};
      #pragma unroll
      for (int hh = 0; hh < 4; ++hh)
        #pragma unroll
        for (int j = 0; j < 8; ++j)
          acc[j] = fmaf(ss[hh], W1o[(fbase + j) * HD + h4 * 4 + hh], acc[j]);
    }
    #pragma unroll
    for (int j = 0; j < 8; ++j) xch[fbase + j][tokloc] = fmaxf(acc[j], 0.0f);
    __syncthreads();                                      // h1 ready for all fg

    const float* __restrict__ W2o = W2T + mb;
    const float* __restrict__ b2o = b2 + (t * ON + o) * HD;
    float acc2[8];
    #pragma unroll
    for (int j = 0; j < 8; ++j) acc2[j] = b2o[fbase + j];
    for (int h4 = 0; h4 < HD / 4; ++h4) {
      float hv[4];
      #pragma unroll
      for (int hh = 0; hh < 4; ++hh) hv[hh] = xch[h4 * 4 + hh][tokloc];
      #pragma unroll
      for (int hh = 0; hh < 4; ++hh)
        #pragma unroll
        for (int j = 0; j < 8; ++j)
          acc2[j] = fmaf(hv[hh], W2o[(fbase + j) * HD + h4 * 4 + hh], acc2[j]);
    }
    const float wo = hc.w[t][o];
    #pragma unroll
    for (int j = 0; j < 8; ++j) out[j] = fmaf(wo, fmaxf(acc2[j], 0.0f), out[j]);
    __syncthreads();                                      // xch reads done before next-o write
  }

  if (act) {
    float* wrow = states + (size_t)token * HD + fbase;
    #pragma unroll
    for (int q = 0; q < 2; ++q) {
      float4 v; v.x = out[q*4]; v.y = out[q*4+1]; v.z = out[q*4+2]; v.w = out[q*4+3];
      *(float4*)(wrow + q * 4) = v;
    }
  }

  if (hc.last_hop) return;    // uniform exit; routing result unused

  // routing: exchange out through xch, r1 = relu(out @ rW1 + rb1)
  #pragma unroll
  for (int j = 0; j < 8; ++j) xch[fbase + j][tokloc] = out[j];
  __syncthreads();
  float acc3[8];
  #pragma unroll
  for (int j = 0; j < 8; ++j) acc3[j] = rb1[fbase + j];
  for (int h4 = 0; h4 < HD / 4; ++h4) {
    float hv[4];
    #pragma unroll
    for (int hh = 0; hh < 4; ++hh) hv[hh] = xch[h4 * 4 + hh][tokloc];
    #pragma unroll
    for (int hh = 0; hh < 4; ++hh)
      #pragma unroll
      for (int j = 0; j < 8; ++j)
        acc3[j] = fmaf(hv[hh], rW1T[(fbase + j) * HD + h4 * 4 + hh], acc3[j]);
  }
  __syncthreads();            // out reads done; overwrite xch with r1
  #pragma unroll
  for (int j = 0; j < 8; ++j) xch[fbase + j][tokloc] = fmaxf(acc3[j], 0.0f);
  __syncthreads();

  // stripe 0: logits = r1 @ rW2 + rb2, gumbel-argmax sample (lane = token)
  int bc = 0;
  if (fg == 0) {
    float lg[NCAT];
    #pragma unroll
    for (int c = 0; c < NCAT; ++c) lg[c] = rb2[c];
    for (int h4 = 0; h4 < HD / 4; ++h4) {
      float hv[4];
      #pragma unroll
      for (int hh = 0; hh < 4; ++hh) hv[hh] = xch[h4 * 4 + hh][tokloc];
      #pragma unroll
      for (int hh = 0; hh < 4; ++hh)
        #pragma unroll
        for (int c = 0; c < NCAT; ++c)
          lg[c] = fmaf(hv[hh], rW2T[c * HD + h4 * 4 + hh], lg[c]);
    }
    const unsigned jb = (unsigned)token * (unsigned)NCAT;
    float best = -3.0e38f;
    #pragma unroll
    for (int c = 0; c < NCAT; ++c) {
      const unsigned bits = tf_bits32(hc.ck0, hc.ck1, jb + (unsigned)c);
      const float u = __uint_as_float((bits >> 9) | 0x3f800000u) - 1.0f;
      float val = u + 1.17549435e-38f;
      val = fmaxf(val, 1.17549435e-38f);
      const float g = -logf(-logf(val));
      const float sc = lg[c] + g;
      if (sc > best) { best = sc; bc = c; }   // strict > keeps first max
    }
  }
  if (tid < TN) lcnt[tid] = 0;
  __syncthreads();
  if (fg == 0 && act) {
    const int nt = bc < (TN - 1) ? bc : (TN - 1);
    tempers[token] = nt;
    if (bc == TN) done[token] = 1;
    else atomicAdd(&lcnt[nt], 1);
  }
  __syncthreads();
  if (tid < TN && lcnt[tid] > 0) atomicAdd(&cnt_next[tid], lcnt[tid]);
}

// pred = states @ pred_W + pred_b; err = mean((pred-x)^2). Wave per token.
__global__ __launch_bounds__(TPB, 2) void k_pred(
    const float* __restrict__ states, const float* __restrict__ x,
    const float* __restrict__ pW, const float* __restrict__ pb,
    float* __restrict__ pred, float* __restrict__ err)
{
  const int tid = threadIdx.x;
  const int lane = tid & 63;
  int n = blockIdx.x * 4 + (tid >> 6);
  n = __builtin_amdgcn_readfirstlane(n);
  const float* srow = states + (size_t)n * HD;
  float a0 = pb[lane], a1 = pb[64 + lane];
  for (int h = 0; h < HD; ++h) {
    const float sh = srow[h];                       // wave-uniform -> s_load
    a0 = fmaf(sh, pW[h * DIN + lane], a0);
    a1 = fmaf(sh, pW[h * DIN + 64 + lane], a1);
  }
  pred[(size_t)n * DIN + lane] = a0;
  pred[(size_t)n * DIN + 64 + lane] = a1;
  const float x0v = x[(size_t)n * DIN + lane];
  const float x1v = x[(size_t)n * DIN + 64 + lane];
  const float d0 = a0 - x0v, d1 = a1 - x1v;
  float s = fmaf(d0, d0, d1 * d1);
  #pragma unroll
  for (int off = 32; off > 0; off >>= 1) s += __shfl_xor(s, off, 64);
  if (lane == 0) err[n] = s * (1.0f / 128.0f);
}

// ---- host-side RNG constant derivation (deterministic, capture-safe) ----
static float host_erfinv(float xf) {     // XLA ErfInv32 (Giles) polynomial
  double x = xf;
  double w = -log1p(-x * x);
  double p;
  if (w < 5.0) {
    w -= 2.5;
    p = 2.81022636e-08;          p = 3.43273939e-07 + p * w;
    p = -3.5233877e-06 + p * w;  p = -4.39150654e-06 + p * w;
    p = 0.00021858087 + p * w;   p = -0.00125372503 + p * w;
    p = -0.00417768164 + p * w;  p = 0.246640727 + p * w;
    p = 1.50140941 + p * w;
  } else {
    w = sqrt(w) - 3.0;
    p = -0.000200214257;         p = 0.000100950558 + p * w;
    p = 0.00134934322 + p * w;   p = -0.00367342844 + p * w;
    p = 0.00573950773 + p * w;   p = -0.0076224613 + p * w;
    p = 0.00943887047 + p * w;   p = 1.00167406 + p * w;
    p = 2.83297682 + p * w;
  }
  return (float)(p * x);
}

static void build_hops(HopConst* hcs) {
  const float lo = nextafterf(-1.0f, 0.0f);       // -0.99999994
  const unsigned rk0 = 0u, rk1 = 42u;             // jax.random.key(42) -> [0,42]
  for (int hop = 0; hop < NHOPS; ++hop) {
    unsigned hk0, hk1;
    tf2x32(rk0, rk1, 0u, (unsigned)hop, hk0, hk1);          // fold_in(rkey, hop)
    for (int t = 0; t < TN; ++t) {
      unsigned tk0, tk1;
      tf2x32(hk0, hk1, 0u, (unsigned)t, tk0, tk1);          // fold_in(hkey, t)
      double nrm[3];
      for (int i = 0; i < 3; ++i) {
        const unsigned bits = tf_bits32(tk0, tk1, (unsigned)i);
        unsigned ub = (bits >> 9) | 0x3f800000u;
        float f; memcpy(&f, &ub, 4);
        const float u01 = f - 1.0f;
        float val = u01 * 2.0f + lo;                        // (max-min)=2.0f exactly (RNE)
        if (val < lo) val = lo;
        const float ef = host_erfinv(val);
        nrm[i] = (double)(1.41421356f * ef);                // sqrt(2) fp32 const
      }
      const double m = fmax(nrm[0], fmax(nrm[1], nrm[2]));
      const double e0 = exp(nrm[0] - m), e1 = exp(nrm[1] - m), e2 = exp(nrm[2] - m);
      const double s = e0 + e1 + e2;
      hcs[hop].w[t][0] = (float)(e0 / s);
      hcs[hop].w[t][1] = (float)(e1 / s);
      hcs[hop].w[t][2] = (float)(e2 / s);
    }
    unsigned ck0, ck1;
    tf2x32(hk0, hk1, 0u, 10000u, ck0, ck1);                 // fold_in(hkey, 10000)
    hcs[hop].ck0 = ck0; hcs[hop].ck1 = ck1;
    hcs[hop].last_hop = (hop == NHOPS - 1) ? 1 : 0;
  }
}

extern "C" void kernel_launch(void* const* d_in, const int* in_sizes, int n_in,
                              void* d_out, int out_size, void* d_ws, size_t ws_size,
                              hipStream_t stream) {
  (void)in_sizes; (void)n_in; (void)out_size; (void)ws_size;
  const float* x    = (const float*)d_in[0];
  const float* pW   = (const float*)d_in[1];
  const float* pb   = (const float*)d_in[2];
  const float* W1   = (const float*)d_in[3];
  const float* b1   = (const float*)d_in[4];
  const float* W2   = (const float*)d_in[5];
  const float* b2   = (const float*)d_in[6];
  const float* rW1  = (const float*)d_in[7];
  const float* rb1  = (const float*)d_in[8];
  const float* rW2  = (const float*)d_in[9];
  const float* rb2  = (const float*)d_in[10];
  const float* pdW  = (const float*)d_in[11];
  const float* pdb  = (const float*)d_in[12];
  const int*   itmp = (const int*)d_in[13];

  // ws layout: [meta 1KB][tempers N][done N][compact N+TN*64][states N*64]
  //            [W1T 147456][W2T 147456][rW1T 4096][rW2T 832]
  int* meta    = (int*)d_ws;
  int* tempers = (int*)((char*)d_ws + 1024);
  int* done    = tempers + N_TOK;
  int* compact = done + N_TOK;
  float* states = (float*)(compact + N_TOK + TN * TOKB);
  float* W1T  = states + (size_t)N_TOK * HD;
  float* W2T  = W1T + TN * ON * HD * HD;
  float* rW1T = W2T + TN * ON * HD * HD;
  float* rW2T = rW1T + HD * HD;

  HopConst hcs[NHOPS];
  build_hops(hcs);

  hipMemsetAsync(meta, 0, 160 * sizeof(int), stream);
  k_tr<<<(TN * ON * HD * HD + TPB - 1) / TPB, TPB, 0, stream>>>(
      W1, W2, rW1, rW2, W1T, W2T, rW1T, rW2T);
  k_init<<<N_TOK / TPB, TPB, 0, stream>>>(x, pW, pb, itmp, states, tempers, done, meta);
  for (int h = 0; h < NHOPS; ++h) {
    int* cnt_h = meta + h * TN;
    int* cnt_n = meta + (h + 1) * TN;
    int* cur_h = meta + 60 + h * TN;
    int* off_h = meta + 108 + h * (TN + 1);
    k_prefix<<<1, 64, 0, stream>>>(cnt_h, off_h);
    k_scatter<<<N_TOK / TPB, TPB, 0, stream>>>(tempers, done, off_h, cur_h, compact);
    k_hop<<<N_TOK / TOKB + TN, TPB_HOP, 0, stream>>>(states, tempers, done, compact, cnt_h, off_h,
        W1T, b1, W2T, b2, rW1T, rb1, rW2T, rb2, cnt_n, hcs[h]);
  }
  float* pred = (float*)d_out;
  float* errp = pred + (size_t)N_TOK * DIN;
  k_pred<<<N_TOK / 4, TPB, 0, stream>>>(states, x, pdW, pdb, pred, errp);
}

// Round 5
// 562.148 us; speedup vs baseline: 1.0325x; 1.0325x over previous
//
#include <hip/hip_runtime.h>
#include <cstring>
#include <cmath>
#include <cstdint>

#define N_TOK 65536
#define DIN 128
#define HD 64
#define TN 12
#define ON 3
#define NHOPS 4
#define TPB 256
#define TPB_HOP 512      // 8 waves
#define TOKB 256         // tokens per k_hop block; thread tile = 8 feat x 4 tok
#define NCAT 13

struct HopConst {
  float w[TN][ON];     // softmax mixture weights per temper
  unsigned ck0, ck1;   // categorical key for this hop
  int last_hop;
};

// ---- threefry2x32 (exact JAX semantics) ----
__host__ __device__ __forceinline__ void tf2x32(unsigned k0, unsigned k1,
                                                unsigned x0, unsigned x1,
                                                unsigned& o0, unsigned& o1) {
  unsigned ks2 = k0 ^ k1 ^ 0x1BD11BDAu;
  x0 += k0; x1 += k1;
#define TFR(r) { x0 += x1; x1 = (x1 << (r)) | (x1 >> (32 - (r))); x1 ^= x0; }
  TFR(13) TFR(15) TFR(26) TFR(6)
  x0 += k1;  x1 += ks2 + 1u;
  TFR(17) TFR(29) TFR(16) TFR(24)
  x0 += ks2; x1 += k0 + 2u;
  TFR(13) TFR(15) TFR(26) TFR(6)
  x0 += k0;  x1 += k1 + 3u;
  TFR(17) TFR(29) TFR(16) TFR(24)
  x0 += k1;  x1 += ks2 + 4u;
  TFR(13) TFR(15) TFR(26) TFR(6)
  x0 += ks2; x1 += k0 + 5u;
#undef TFR
  o0 = x0; o1 = x1;
}

// partitionable-mode 32-bit random bits, element j: o0^o1 of tf(key, 0, j)
__host__ __device__ __forceinline__ unsigned tf_bits32(unsigned k0, unsigned k1, unsigned j) {
  unsigned o0, o1;
  tf2x32(k0, k1, 0u, j, o0, o1);
  return o0 ^ o1;
}

// ---- kernels ----

// proj: states = x @ proj_W + proj_b; init tempers/done; histogram cnt0
__global__ __launch_bounds__(TPB, 2) void k_init(
    const float* __restrict__ x, const float* __restrict__ pW,
    const float* __restrict__ pb, const int* __restrict__ itemp,
    float* __restrict__ states, int* __restrict__ tempers,
    int* __restrict__ done, int* __restrict__ cnt0)
{
  __shared__ int lcnt[TN];
  const int tid = threadIdx.x;
  if (tid < TN) lcnt[tid] = 0;
  __syncthreads();
  const int n = blockIdx.x * TPB + tid;
  float acc[HD];
  #pragma unroll
  for (int k = 0; k < HD; ++k) acc[k] = pb[k];
  const float* xrow = x + (size_t)n * DIN;
  for (int d4 = 0; d4 < DIN / 4; ++d4) {
    const float4 xv = *(const float4*)(xrow + d4 * 4);
    const float xs[4] = {xv.x, xv.y, xv.z, xv.w};
    #pragma unroll
    for (int dd = 0; dd < 4; ++dd) {
      const float* wr = pW + (d4 * 4 + dd) * HD;   // wave-uniform -> s_load
      #pragma unroll
      for (int k = 0; k < HD; ++k) acc[k] = fmaf(xs[dd], wr[k], acc[k]);
    }
  }
  float* srow = states + (size_t)n * HD;
  #pragma unroll
  for (int k4 = 0; k4 < HD / 4; ++k4) {
    float4 v; v.x = acc[k4*4]; v.y = acc[k4*4+1]; v.z = acc[k4*4+2]; v.w = acc[k4*4+3];
    *(float4*)(srow + k4 * 4) = v;
  }
  const int t = itemp[n];
  tempers[n] = t;
  done[n] = 0;
  atomicAdd(&lcnt[t], 1);
  __syncthreads();
  if (tid < TN && lcnt[tid] > 0) atomicAdd(&cnt0[tid], lcnt[tid]);
}

// pad route_W2 [64][13] -> [64][16] (and rb2 -> 16) for aligned scalar x8 loads
__global__ __launch_bounds__(TPB) void k_pad(
    const float* __restrict__ rW2, const float* __restrict__ rb2,
    float* __restrict__ rW2P, float* __restrict__ rb2P)
{
  const int i = blockIdx.x * TPB + threadIdx.x;
  if (i < HD * 16) {
    const int h = i >> 4, c = i & 15;
    rW2P[i] = (c < NCAT) ? rW2[h * NCAT + c] : 0.0f;
  }
  if (i < 16) rb2P[i] = (i < NCAT) ? rb2[i] : 0.0f;
}

// 256-padded prefix offsets over temper counts
__global__ void k_prefix(const int* __restrict__ cnt, int* __restrict__ offp) {
  if (threadIdx.x == 0 && blockIdx.x == 0) {
    int o = 0;
    for (int t = 0; t < TN; ++t) { offp[t] = o; o += (cnt[t] + TOKB - 1) & ~(TOKB - 1); }
    offp[TN] = o;
  }
}

// scatter active tokens into per-temper compact regions
__global__ __launch_bounds__(TPB) void k_scatter(
    const int* __restrict__ tempers, const int* __restrict__ done,
    const int* __restrict__ offp, int* __restrict__ cursor, int* __restrict__ compact)
{
  __shared__ int lcnt[TN], lbase[TN];
  const int tid = threadIdx.x;
  if (tid < TN) lcnt[tid] = 0;
  __syncthreads();
  const int n = blockIdx.x * TPB + tid;
  int t = -1, lpos = 0;
  if (!done[n]) { t = tempers[n]; lpos = atomicAdd(&lcnt[t], 1); }
  __syncthreads();
  if (tid < TN && lcnt[tid] > 0) lbase[tid] = atomicAdd(&cursor[tid], lcnt[tid]);
  __syncthreads();
  if (t >= 0) compact[offp[t] + lbase[t] + lpos] = n;
}

// main per-hop kernel: register-tiled 8x4 per thread, 256-token block,
// weights on scalar path reused 4x per fetch, acts via LDS.
__global__ __launch_bounds__(TPB_HOP, 2) void k_hop(
    float* __restrict__ states, int* __restrict__ tempers, int* __restrict__ done,
    const int* __restrict__ compact, const int* __restrict__ cnt,
    const int* __restrict__ offp,
    const float* __restrict__ W1, const float* __restrict__ b1,
    const float* __restrict__ W2, const float* __restrict__ b2,
    const float* __restrict__ rW1, const float* __restrict__ rb1,
    const float* __restrict__ rW2P, const float* __restrict__ rb2P,
    int* __restrict__ cnt_next, HopConst hc)
{
  __shared__ float sA[HD][TOKB];        // states tile, later r1 (64 KB)
  __shared__ float sB[HD][TOKB];        // h1 / out / logits (64 KB)
  __shared__ int stok[TOKB];
  __shared__ unsigned char sact[TOKB];
  __shared__ int lcnt[TN];

  const int tid = threadIdx.x;
  const int lane = tid & 63;
  const int fg = __builtin_amdgcn_readfirstlane(tid >> 6);  // wave id 0..7
  const int jb = fg * 8;                                    // feature-stripe base
  const int bstart = blockIdx.x * TOKB;
  if (bstart >= offp[TN]) return;
  int tt = 0;
  #pragma unroll
  for (int i = 1; i < TN; ++i) if (bstart >= offp[i]) tt = i;
  const int t = __builtin_amdgcn_readfirstlane(tt);
  const int cntt = cnt[t];

  // ---- stage states tile + token ids ----
  {
    const int slot = tid & 255;
    const int half = tid >> 8;
    const int pos = bstart + slot;
    const bool a = (pos - offp[t]) < cntt;
    const int tok = compact[a ? pos : offp[t]];
    if (half == 0) { stok[slot] = tok; sact[slot] = a ? 1 : 0; }
    const float* sr = states + (size_t)tok * HD + half * 32;
    #pragma unroll
    for (int i = 0; i < 8; ++i) {
      const float4 v = *(const float4*)(sr + i * 4);
      sA[half*32 + i*4 + 0][slot] = v.x;
      sA[half*32 + i*4 + 1][slot] = v.y;
      sA[half*32 + i*4 + 2][slot] = v.z;
      sA[half*32 + i*4 + 3][slot] = v.w;
    }
  }
  if (tid < TN) lcnt[tid] = 0;
  __syncthreads();

  float out[8][4];
  #pragma unroll
  for (int j = 0; j < 8; ++j)
    #pragma unroll
    for (int q = 0; q < 4; ++q) out[j][q] = 0.0f;

  #pragma unroll 1
  for (int o = 0; o < ON; ++o) {
    const size_t mb = ((size_t)(t * ON + o)) << 12;
    // ---- layer 1: acts sA -> h1 sB ----
    {
      const float* __restrict__ Wo = W1 + mb;            // [h][j] rows
      const float* __restrict__ bo = b1 + (t * ON + o) * HD;
      float acc[8][4];
      #pragma unroll
      for (int j = 0; j < 8; ++j) {
        const float bv = bo[jb + j];
        #pragma unroll
        for (int q = 0; q < 4; ++q) acc[j][q] = bv;
      }
      #pragma unroll 4
      for (int h4 = 0; h4 < 16; ++h4) {
        float av[4][4];
        #pragma unroll
        for (int hh = 0; hh < 4; ++hh)
          #pragma unroll
          for (int q = 0; q < 4; ++q)
            av[hh][q] = sA[h4 * 4 + hh][lane + 64 * q];
        #pragma unroll
        for (int hh = 0; hh < 4; ++hh) {
          const float* wr = Wo + (h4 * 4 + hh) * HD + jb;   // uniform -> s_load x8
          #pragma unroll
          for (int j = 0; j < 8; ++j) {
            const float wv = wr[j];
            #pragma unroll
            for (int q = 0; q < 4; ++q)
              acc[j][q] = fmaf(wv, av[hh][q], acc[j][q]);
          }
        }
      }
      #pragma unroll
      for (int j = 0; j < 8; ++j)
        #pragma unroll
        for (int q = 0; q < 4; ++q)
          sB[jb + j][lane + 64 * q] = fmaxf(acc[j][q], 0.0f);
    }
    __syncthreads();
    // ---- layer 2: acts sB -> out (regs) ----
    {
      const float* __restrict__ Wo = W2 + mb;
      const float* __restrict__ bo = b2 + (t * ON + o) * HD;
      float acc[8][4];
      #pragma unroll
      for (int j = 0; j < 8; ++j) {
        const float bv = bo[jb + j];
        #pragma unroll
        for (int q = 0; q < 4; ++q) acc[j][q] = bv;
      }
      #pragma unroll 4
      for (int h4 = 0; h4 < 16; ++h4) {
        float av[4][4];
        #pragma unroll
        for (int hh = 0; hh < 4; ++hh)
          #pragma unroll
          for (int q = 0; q < 4; ++q)
            av[hh][q] = sB[h4 * 4 + hh][lane + 64 * q];
        #pragma unroll
        for (int hh = 0; hh < 4; ++hh) {
          const float* wr = Wo + (h4 * 4 + hh) * HD + jb;
          #pragma unroll
          for (int j = 0; j < 8; ++j) {
            const float wv = wr[j];
            #pragma unroll
            for (int q = 0; q < 4; ++q)
              acc[j][q] = fmaf(wv, av[hh][q], acc[j][q]);
          }
        }
      }
      const float wo = hc.w[t][o];
      #pragma unroll
      for (int j = 0; j < 8; ++j)
        #pragma unroll
        for (int q = 0; q < 4; ++q)
          out[j][q] = fmaf(wo, fmaxf(acc[j][q], 0.0f), out[j][q]);
    }
    __syncthreads();          // sB reads done before next-o h1 write
  }

  // ---- out -> sB; store new states ----
  #pragma unroll
  for (int j = 0; j < 8; ++j)
    #pragma unroll
    for (int q = 0; q < 4; ++q)
      sB[jb + j][lane + 64 * q] = out[j][q];
  __syncthreads();
  {
    const int slot = tid & 255;
    const int half = tid >> 8;
    if (sact[slot]) {
      float* wr = states + (size_t)stok[slot] * HD + half * 32;
      #pragma unroll
      for (int i = 0; i < 8; ++i) {
        float4 v;
        v.x = sB[half*32 + i*4 + 0][slot];
        v.y = sB[half*32 + i*4 + 1][slot];
        v.z = sB[half*32 + i*4 + 2][slot];
        v.w = sB[half*32 + i*4 + 3][slot];
        *(float4*)(wr + i * 4) = v;
      }
    }
  }

  if (hc.last_hop) return;    // uniform; routing unused on final hop

  // ---- r1 = relu(out @ rW1 + rb1): acts sB -> sA ----
  {
    float acc[8][4];
    #pragma unroll
    for (int j = 0; j < 8; ++j) {
      const float bv = rb1[jb + j];
      #pragma unroll
      for (int q = 0; q < 4; ++q) acc[j][q] = bv;
    }
    #pragma unroll 4
    for (int h4 = 0; h4 < 16; ++h4) {
      float av[4][4];
      #pragma unroll
      for (int hh = 0; hh < 4; ++hh)
        #pragma unroll
        for (int q = 0; q < 4; ++q)
          av[hh][q] = sB[h4 * 4 + hh][lane + 64 * q];
      #pragma unroll
      for (int hh = 0; hh < 4; ++hh) {
        const float* wr = rW1 + (h4 * 4 + hh) * HD + jb;
        #pragma unroll
        for (int j = 0; j < 8; ++j) {
          const float wv = wr[j];
          #pragma unroll
          for (int q = 0; q < 4; ++q)
            acc[j][q] = fmaf(wv, av[hh][q], acc[j][q]);
        }
      }
    }
    // sA (states) has no readers anymore; safe to overwrite without barrier
    #pragma unroll
    for (int j = 0; j < 8; ++j)
      #pragma unroll
      for (int q = 0; q < 4; ++q)
        sA[jb + j][lane + 64 * q] = fmaxf(acc[j][q], 0.0f);
  }
  __syncthreads();

  // ---- logits = r1 @ rW2 + rb2: acts sA -> sB[0..12][tok] ----
  {
    const int cg = fg & 1;        // 0: c=0..7, 1: c=8..12
    const int qw = fg >> 1;       // token quarter
    const int cb = cg * 8;
    float lg[8];
    #pragma unroll
    for (int c = 0; c < 8; ++c) lg[c] = rb2P[cb + c];
    #pragma unroll 4
    for (int h4 = 0; h4 < 16; ++h4) {
      float av[4];
      #pragma unroll
      for (int hh = 0; hh < 4; ++hh)
        av[hh] = sA[h4 * 4 + hh][lane + 64 * qw];
      #pragma unroll
      for (int hh = 0; hh < 4; ++hh) {
        const float* wr = rW2P + (h4 * 4 + hh) * 16 + cb;   // padded rows
        #pragma unroll
        for (int c = 0; c < 8; ++c)
          lg[c] = fmaf(wr[c], av[hh], lg[c]);
      }
    }
    #pragma unroll
    for (int c = 0; c < 8; ++c)
      if (cb + c < NCAT) sB[cb + c][lane + 64 * qw] = lg[c];
  }
  __syncthreads();

  // ---- gumbel-argmax sample, one thread per token slot ----
  if (tid < TOKB) {
    const int slot = tid;
    if (sact[slot]) {
      const int token = stok[slot];
      const unsigned jbase = (unsigned)token * (unsigned)NCAT;
      float best = -3.0e38f; int bc = 0;
      #pragma unroll
      for (int c = 0; c < NCAT; ++c) {
        const float L = sB[c][slot];
        const unsigned bits = tf_bits32(hc.ck0, hc.ck1, jbase + (unsigned)c);
        const float u = __uint_as_float((bits >> 9) | 0x3f800000u) - 1.0f;
        float val = u + 1.17549435e-38f;
        val = fmaxf(val, 1.17549435e-38f);
        const float g = -logf(-logf(val));
        const float sc = L + g;
        if (sc > best) { best = sc; bc = c; }   // strict > keeps first max
      }
      const int nt = bc < (TN - 1) ? bc : (TN - 1);
      tempers[token] = nt;
      if (bc == TN) done[token] = 1;
      else atomicAdd(&lcnt[nt], 1);
    }
  }
  __syncthreads();
  if (tid < TN && lcnt[tid] > 0) atomicAdd(&cnt_next[tid], lcnt[tid]);
}

// pred = states @ pred_W + pred_b; err = mean((pred-x)^2). Wave per token.
__global__ __launch_bounds__(TPB, 2) void k_pred(
    const float* __restrict__ states, const float* __restrict__ x,
    const float* __restrict__ pW, const float* __restrict__ pb,
    float* __restrict__ pred, float* __restrict__ err)
{
  const int tid = threadIdx.x;
  const int lane = tid & 63;
  int n = blockIdx.x * 4 + (tid >> 6);
  n = __builtin_amdgcn_readfirstlane(n);
  const float* srow = states + (size_t)n * HD;
  float a0 = pb[lane], a1 = pb[64 + lane];
  for (int h = 0; h < HD; ++h) {
    const float sh = srow[h];                       // wave-uniform -> s_load
    a0 = fmaf(sh, pW[h * DIN + lane], a0);
    a1 = fmaf(sh, pW[h * DIN + 64 + lane], a1);
  }
  pred[(size_t)n * DIN + lane] = a0;
  pred[(size_t)n * DIN + 64 + lane] = a1;
  const float x0v = x[(size_t)n * DIN + lane];
  const float x1v = x[(size_t)n * DIN + 64 + lane];
  const float d0 = a0 - x0v, d1 = a1 - x1v;
  float s = fmaf(d0, d0, d1 * d1);
  #pragma unroll
  for (int off = 32; off > 0; off >>= 1) s += __shfl_xor(s, off, 64);
  if (lane == 0) err[n] = s * (1.0f / 128.0f);
}

// ---- host-side RNG constant derivation (deterministic, capture-safe) ----
static float host_erfinv(float xf) {     // XLA ErfInv32 (Giles) polynomial
  double x = xf;
  double w = -log1p(-x * x);
  double p;
  if (w < 5.0) {
    w -= 2.5;
    p = 2.81022636e-08;          p = 3.43273939e-07 + p * w;
    p = -3.5233877e-06 + p * w;  p = -4.39150654e-06 + p * w;
    p = 0.00021858087 + p * w;   p = -0.00125372503 + p * w;
    p = -0.00417768164 + p * w;  p = 0.246640727 + p * w;
    p = 1.50140941 + p * w;
  } else {
    w = sqrt(w) - 3.0;
    p = -0.000200214257;         p = 0.000100950558 + p * w;
    p = 0.00134934322 + p * w;   p = -0.00367342844 + p * w;
    p = 0.00573950773 + p * w;   p = -0.0076224613 + p * w;
    p = 0.00943887047 + p * w;   p = 1.00167406 + p * w;
    p = 2.83297682 + p * w;
  }
  return (float)(p * x);
}

static void build_hops(HopConst* hcs) {
  const float lo = nextafterf(-1.0f, 0.0f);       // -0.99999994
  const unsigned rk0 = 0u, rk1 = 42u;             // jax.random.key(42) -> [0,42]
  for (int hop = 0; hop < NHOPS; ++hop) {
    unsigned hk0, hk1;
    tf2x32(rk0, rk1, 0u, (unsigned)hop, hk0, hk1);          // fold_in(rkey, hop)
    for (int t = 0; t < TN; ++t) {
      unsigned tk0, tk1;
      tf2x32(hk0, hk1, 0u, (unsigned)t, tk0, tk1);          // fold_in(hkey, t)
      double nrm[3];
      for (int i = 0; i < 3; ++i) {
        const unsigned bits = tf_bits32(tk0, tk1, (unsigned)i);
        unsigned ub = (bits >> 9) | 0x3f800000u;
        float f; memcpy(&f, &ub, 4);
        const float u01 = f - 1.0f;
        float val = u01 * 2.0f + lo;                        // (max-min)=2.0f exactly (RNE)
        if (val < lo) val = lo;
        const float ef = host_erfinv(val);
        nrm[i] = (double)(1.41421356f * ef);                // sqrt(2) fp32 const
      }
      const double m = fmax(nrm[0], fmax(nrm[1], nrm[2]));
      const double e0 = exp(nrm[0] - m), e1 = exp(nrm[1] - m), e2 = exp(nrm[2] - m);
      const double s = e0 + e1 + e2;
      hcs[hop].w[t][0] = (float)(e0 / s);
      hcs[hop].w[t][1] = (float)(e1 / s);
      hcs[hop].w[t][2] = (float)(e2 / s);
    }
    unsigned ck0, ck1;
    tf2x32(hk0, hk1, 0u, 10000u, ck0, ck1);                 // fold_in(hkey, 10000)
    hcs[hop].ck0 = ck0; hcs[hop].ck1 = ck1;
    hcs[hop].last_hop = (hop == NHOPS - 1) ? 1 : 0;
  }
}

extern "C" void kernel_launch(void* const* d_in, const int* in_sizes, int n_in,
                              void* d_out, int out_size, void* d_ws, size_t ws_size,
                              hipStream_t stream) {
  (void)in_sizes; (void)n_in; (void)out_size; (void)ws_size;
  const float* x    = (const float*)d_in[0];
  const float* pW   = (const float*)d_in[1];
  const float* pb   = (const float*)d_in[2];
  const float* W1   = (const float*)d_in[3];
  const float* b1   = (const float*)d_in[4];
  const float* W2   = (const float*)d_in[5];
  const float* b2   = (const float*)d_in[6];
  const float* rW1  = (const float*)d_in[7];
  const float* rb1  = (const float*)d_in[8];
  const float* rW2  = (const float*)d_in[9];
  const float* rb2  = (const float*)d_in[10];
  const float* pdW  = (const float*)d_in[11];
  const float* pdb  = (const float*)d_in[12];
  const int*   itmp = (const int*)d_in[13];

  // ws layout: [meta 1KB][tempers N][done N][compact N+TN*TOKB][states N*64]
  //            [rW2P 1024][rb2P 16]
  int* meta    = (int*)d_ws;
  int* tempers = (int*)((char*)d_ws + 1024);
  int* done    = tempers + N_TOK;
  int* compact = done + N_TOK;
  float* states = (float*)(compact + N_TOK + TN * TOKB);
  float* rW2P  = states + (size_t)N_TOK * HD;
  float* rb2P  = rW2P + HD * 16;

  HopConst hcs[NHOPS];
  build_hops(hcs);

  hipMemsetAsync(meta, 0, 160 * sizeof(int), stream);
  k_pad<<<4, TPB, 0, stream>>>(rW2, rb2, rW2P, rb2P);
  k_init<<<N_TOK / TPB, TPB, 0, stream>>>(x, pW, pb, itmp, states, tempers, done, meta);
  for (int h = 0; h < NHOPS; ++h) {
    int* cnt_h = meta + h * TN;
    int* cnt_n = meta + (h + 1) * TN;
    int* cur_h = meta + 60 + h * TN;
    int* off_h = meta + 108 + h * (TN + 1);
    k_prefix<<<1, 64, 0, stream>>>(cnt_h, off_h);
    k_scatter<<<N_TOK / TPB, TPB, 0, stream>>>(tempers, done, off_h, cur_h, compact);
    k_hop<<<N_TOK / TOKB + TN, TPB_HOP, 0, stream>>>(states, tempers, done, compact, cnt_h, off_h,
        W1, b1, W2, b2, rW1, rb1, rW2P, rb2P, cnt_n, hcs[h]);
  }
  float* pred = (float*)d_out;
  float* errp = pred + (size_t)N_TOK * DIN;
  k_pred<<<N_TOK / 4, TPB, 0, stream>>>(states, x, pdW, pdb, pred, errp);
}

// Round 6
// 502.420 us; speedup vs baseline: 1.1553x; 1.1189x over previous
//
#include <hip/hip_runtime.h>
#include <cstring>
#include <cmath>
#include <cstdint>

#define N_TOK 65536
#define DIN 128
#define HD 64
#define TN 12
#define ON 3
#define NHOPS 4
#define TPB 256
#define TPB_HOP 512      // 8 waves; thread tile = 8 feat x 4 tok
#define TOKB 256         // tokens per k_hop block
#define NCAT 13

struct HopConst {
  float w[TN][ON];     // softmax mixture weights per temper
  unsigned ck0, ck1;   // categorical key for this hop
  int last_hop;
};

// ---- threefry2x32 (exact JAX semantics) ----
__host__ __device__ __forceinline__ void tf2x32(unsigned k0, unsigned k1,
                                                unsigned x0, unsigned x1,
                                                unsigned& o0, unsigned& o1) {
  unsigned ks2 = k0 ^ k1 ^ 0x1BD11BDAu;
  x0 += k0; x1 += k1;
#define TFR(r) { x0 += x1; x1 = (x1 << (r)) | (x1 >> (32 - (r))); x1 ^= x0; }
  TFR(13) TFR(15) TFR(26) TFR(6)
  x0 += k1;  x1 += ks2 + 1u;
  TFR(17) TFR(29) TFR(16) TFR(24)
  x0 += ks2; x1 += k0 + 2u;
  TFR(13) TFR(15) TFR(26) TFR(6)
  x0 += k0;  x1 += k1 + 3u;
  TFR(17) TFR(29) TFR(16) TFR(24)
  x0 += k1;  x1 += ks2 + 4u;
  TFR(13) TFR(15) TFR(26) TFR(6)
  x0 += ks2; x1 += k0 + 5u;
#undef TFR
  o0 = x0; o1 = x1;
}

// partitionable-mode 32-bit random bits, element j: o0^o1 of tf(key, 0, j)
__host__ __device__ __forceinline__ unsigned tf_bits32(unsigned k0, unsigned k1, unsigned j) {
  unsigned o0, o1;
  tf2x32(k0, k1, 0u, j, o0, o1);
  return o0 ^ o1;
}

// ---- kernels ----

// proj: states = x @ proj_W + proj_b; init tempers/done; histogram cnt0
__global__ __launch_bounds__(TPB, 2) void k_init(
    const float* __restrict__ x, const float* __restrict__ pW,
    const float* __restrict__ pb, const int* __restrict__ itemp,
    float* __restrict__ states, int* __restrict__ tempers,
    int* __restrict__ done, int* __restrict__ cnt0)
{
  __shared__ int lcnt[TN];
  const int tid = threadIdx.x;
  if (tid < TN) lcnt[tid] = 0;
  __syncthreads();
  const int n = blockIdx.x * TPB + tid;
  float acc[HD];
  #pragma unroll
  for (int k = 0; k < HD; ++k) acc[k] = pb[k];
  const float* xrow = x + (size_t)n * DIN;
  for (int d4 = 0; d4 < DIN / 4; ++d4) {
    const float4 xv = *(const float4*)(xrow + d4 * 4);
    const float xs[4] = {xv.x, xv.y, xv.z, xv.w};
    #pragma unroll
    for (int dd = 0; dd < 4; ++dd) {
      const float* wr = pW + (d4 * 4 + dd) * HD;   // wave-uniform -> s_load
      #pragma unroll
      for (int k = 0; k < HD; ++k) acc[k] = fmaf(xs[dd], wr[k], acc[k]);
    }
  }
  float* srow = states + (size_t)n * HD;
  #pragma unroll
  for (int k4 = 0; k4 < HD / 4; ++k4) {
    float4 v; v.x = acc[k4*4]; v.y = acc[k4*4+1]; v.z = acc[k4*4+2]; v.w = acc[k4*4+3];
    *(float4*)(srow + k4 * 4) = v;
  }
  const int t = itemp[n];
  tempers[n] = t;
  done[n] = 0;
  atomicAdd(&lcnt[t], 1);
  __syncthreads();
  if (tid < TN && lcnt[tid] > 0) atomicAdd(&cnt0[tid], lcnt[tid]);
}

// TOKB-padded prefix offsets over temper counts
__global__ void k_prefix(const int* __restrict__ cnt, int* __restrict__ offp) {
  if (threadIdx.x == 0 && blockIdx.x == 0) {
    int o = 0;
    for (int t = 0; t < TN; ++t) { offp[t] = o; o += (cnt[t] + TOKB - 1) & ~(TOKB - 1); }
    offp[TN] = o;
  }
}

// scatter active tokens into per-temper compact regions
__global__ __launch_bounds__(TPB) void k_scatter(
    const int* __restrict__ tempers, const int* __restrict__ done,
    const int* __restrict__ offp, int* __restrict__ cursor, int* __restrict__ compact)
{
  __shared__ int lcnt[TN], lbase[TN];
  const int tid = threadIdx.x;
  if (tid < TN) lcnt[tid] = 0;
  __syncthreads();
  const int n = blockIdx.x * TPB + tid;
  int t = -1, lpos = 0;
  if (!done[n]) { t = tempers[n]; lpos = atomicAdd(&lcnt[t], 1); }
  __syncthreads();
  if (tid < TN && lcnt[tid] > 0) lbase[tid] = atomicAdd(&cursor[tid], lcnt[tid]);
  __syncthreads();
  if (t >= 0) compact[offp[t] + lbase[t] + lpos] = n;
}

// stage a 64x64 fp32 weight matrix (row-major [h][j]) into LDS via vector path
__device__ __forceinline__ void stage_w(const float* __restrict__ g, float* sW, int tid) {
  #pragma unroll
  for (int i = 0; i < 2; ++i) {
    const float4 v = *(const float4*)(g + i * 2048 + tid * 4);
    *(float4*)(sW + i * 2048 + tid * 4) = v;
  }
}

// 8x4 register-tile GEMM step: acc[j][q] += sum_h sW[h][jb+j] * acts[h][tx+64q]
// acts packed [16][TOKB][4]; weight reads are wave-uniform broadcasts.
__device__ __forceinline__ void gemm8x4(const float (*__restrict__ sAct)[TOKB][4],
                                        const float* __restrict__ sW,
                                        int tx, int jb, float acc[8][4])
{
  #pragma unroll 2
  for (int h4 = 0; h4 < 16; ++h4) {
    float4 aq[4];
    #pragma unroll
    for (int q = 0; q < 4; ++q)
      aq[q] = *(const float4*)&sAct[h4][tx + 64 * q][0];
    #pragma unroll
    for (int hh = 0; hh < 4; ++hh) {
      const float4 w0 = *(const float4*)(sW + (h4 * 4 + hh) * HD + jb);
      const float4 w1 = *(const float4*)(sW + (h4 * 4 + hh) * HD + jb + 4);
      const float wv[8] = {w0.x, w0.y, w0.z, w0.w, w1.x, w1.y, w1.z, w1.w};
      #pragma unroll
      for (int j = 0; j < 8; ++j)
        #pragma unroll
        for (int q = 0; q < 4; ++q)
          acc[j][q] = fmaf(wv[j], ((const float*)&aq[q])[hh], acc[j][q]);
    }
  }
}

// main per-hop kernel: all weights through LDS (vector path), no scalar streams
__global__ __launch_bounds__(TPB_HOP, 2) void k_hop(
    float* __restrict__ states, int* __restrict__ tempers, int* __restrict__ done,
    const int* __restrict__ compact, const int* __restrict__ cnt,
    const int* __restrict__ offp,
    const float* __restrict__ W1, const float* __restrict__ b1,
    const float* __restrict__ W2, const float* __restrict__ b2,
    const float* __restrict__ rW1, const float* __restrict__ rb1,
    const float* __restrict__ rW2, const float* __restrict__ rb2,
    int* __restrict__ cnt_next, HopConst hc)
{
  __shared__ float sA[16][TOKB][4];   // packed acts: states, later r1 (64 KB)
  __shared__ float sB[16][TOKB][4];   // h1 / out (64 KB)
  __shared__ float sW[HD * HD];       // staged weight matrix (16 KB)
  __shared__ int stok[TOKB];
  __shared__ unsigned char sact[TOKB];
  __shared__ int lcnt[TN];

  const int tid = threadIdx.x;
  const int tx = tid & 63;                                   // token group (lane)
  const int ty = __builtin_amdgcn_readfirstlane(tid >> 6);   // j-stripe (wave)
  const int jb = ty * 8;
  const int bstart = blockIdx.x * TOKB;
  if (bstart >= offp[TN]) return;
  int tt = 0;
  #pragma unroll
  for (int i = 1; i < TN; ++i) if (bstart >= offp[i]) tt = i;
  const int t = __builtin_amdgcn_readfirstlane(tt);
  const int cntt = cnt[t];

  // ---- stage states tile (packed) + token ids ----
  {
    const int slot = tid & 255;
    const int half = tid >> 8;
    const int pos = bstart + slot;
    const bool a = (pos - offp[t]) < cntt;
    const int tok = compact[a ? pos : offp[t]];
    if (half == 0) { stok[slot] = tok; sact[slot] = a ? 1 : 0; }
    const float* sr = states + (size_t)tok * HD + half * 32;
    #pragma unroll
    for (int i = 0; i < 8; ++i)
      *(float4*)&sA[half * 8 + i][slot][0] = *(const float4*)(sr + i * 4);
  }
  if (tid < TN) lcnt[tid] = 0;

  float out[8][4];
  #pragma unroll
  for (int j = 0; j < 8; ++j)
    #pragma unroll
    for (int q = 0; q < 4; ++q) out[j][q] = 0.0f;

  #pragma unroll 1
  for (int o = 0; o < ON; ++o) {
    const size_t mb = ((size_t)(t * ON + o)) << 12;
    __syncthreads();                          // prev L2 done with sW/sB (o=0: sA staged)
    stage_w(W1 + mb, sW, tid);
    __syncthreads();                          // sW = W1[t,o]
    {
      const float* bo = b1 + (t * ON + o) * HD;
      float acc[8][4];
      #pragma unroll
      for (int j = 0; j < 8; ++j) {
        const float bv = bo[jb + j];
        #pragma unroll
        for (int q = 0; q < 4; ++q) acc[j][q] = bv;
      }
      gemm8x4(sA, sW, tx, jb, acc);
      #pragma unroll
      for (int q = 0; q < 4; ++q) {
        float4 v0, v1;
        v0.x = fmaxf(acc[0][q], 0.0f); v0.y = fmaxf(acc[1][q], 0.0f);
        v0.z = fmaxf(acc[2][q], 0.0f); v0.w = fmaxf(acc[3][q], 0.0f);
        v1.x = fmaxf(acc[4][q], 0.0f); v1.y = fmaxf(acc[5][q], 0.0f);
        v1.z = fmaxf(acc[6][q], 0.0f); v1.w = fmaxf(acc[7][q], 0.0f);
        *(float4*)&sB[ty * 2][tx + 64 * q][0] = v0;
        *(float4*)&sB[ty * 2 + 1][tx + 64 * q][0] = v1;
      }
    }
    __syncthreads();                          // h1 ready; L1's sW reads done
    stage_w(W2 + mb, sW, tid);
    __syncthreads();                          // sW = W2[t,o]
    {
      const float* bo = b2 + (t * ON + o) * HD;
      float acc[8][4];
      #pragma unroll
      for (int j = 0; j < 8; ++j) {
        const float bv = bo[jb + j];
        #pragma unroll
        for (int q = 0; q < 4; ++q) acc[j][q] = bv;
      }
      gemm8x4(sB, sW, tx, jb, acc);
      const float wo = hc.w[t][o];
      #pragma unroll
      for (int j = 0; j < 8; ++j)
        #pragma unroll
        for (int q = 0; q < 4; ++q)
          out[j][q] = fmaf(wo, fmaxf(acc[j][q], 0.0f), out[j][q]);
    }
  }
  __syncthreads();                            // last L2 done reading sB/sW

  // ---- out -> sB (packed); stage rW1 ----
  #pragma unroll
  for (int q = 0; q < 4; ++q) {
    float4 v0, v1;
    v0.x = out[0][q]; v0.y = out[1][q]; v0.z = out[2][q]; v0.w = out[3][q];
    v1.x = out[4][q]; v1.y = out[5][q]; v1.z = out[6][q]; v1.w = out[7][q];
    *(float4*)&sB[ty * 2][tx + 64 * q][0] = v0;
    *(float4*)&sB[ty * 2 + 1][tx + 64 * q][0] = v1;
  }
  if (!hc.last_hop) stage_w(rW1, sW, tid);
  __syncthreads();                            // out tile + sW(rW1) ready

  // ---- coalesced states write-back ----
  {
    const int slot = tid & 255;
    const int half = tid >> 8;
    if (sact[slot]) {
      float* wr = states + (size_t)stok[slot] * HD + half * 32;
      #pragma unroll
      for (int i = 0; i < 8; ++i)
        *(float4*)(wr + i * 4) = *(const float4*)&sB[half * 8 + i][slot][0];
    }
  }

  if (hc.last_hop) return;                    // uniform exit; routing unused

  // ---- r1 = relu(out @ rW1 + rb1): sB -> sA ----
  {
    float acc[8][4];
    #pragma unroll
    for (int j = 0; j < 8; ++j) {
      const float bv = rb1[jb + j];
      #pragma unroll
      for (int q = 0; q < 4; ++q) acc[j][q] = bv;
    }
    gemm8x4(sB, sW, tx, jb, acc);
    #pragma unroll
    for (int q = 0; q < 4; ++q) {
      float4 v0, v1;
      v0.x = fmaxf(acc[0][q], 0.0f); v0.y = fmaxf(acc[1][q], 0.0f);
      v0.z = fmaxf(acc[2][q], 0.0f); v0.w = fmaxf(acc[3][q], 0.0f);
      v1.x = fmaxf(acc[4][q], 0.0f); v1.y = fmaxf(acc[5][q], 0.0f);
      v1.z = fmaxf(acc[6][q], 0.0f); v1.w = fmaxf(acc[7][q], 0.0f);
      *(float4*)&sA[ty * 2][tx + 64 * q][0] = v0;
      *(float4*)&sA[ty * 2 + 1][tx + 64 * q][0] = v1;
    }
  }
  __syncthreads();                            // r1 ready

  // ---- logits + gumbel-argmax, one thread per token slot ----
  if (tid < TOKB) {
    const int slot = tid;
    float lg[NCAT];
    #pragma unroll
    for (int c = 0; c < NCAT; ++c) lg[c] = rb2[c];
    #pragma unroll 4
    for (int h4 = 0; h4 < 16; ++h4) {
      const float4 rv = *(const float4*)&sA[h4][slot][0];
      #pragma unroll
      for (int hh = 0; hh < 4; ++hh) {
        const float av = ((const float*)&rv)[hh];
        const float* wr = rW2 + (h4 * 4 + hh) * NCAT;   // uniform -> s_load (3.3 KB hot)
        #pragma unroll
        for (int c = 0; c < NCAT; ++c)
          lg[c] = fmaf(av, wr[c], lg[c]);
      }
    }
    if (sact[slot]) {
      const int token = stok[slot];
      const unsigned jbase = (unsigned)token * (unsigned)NCAT;
      float best = -3.0e38f; int bc = 0;
      #pragma unroll
      for (int c = 0; c < NCAT; ++c) {
        const unsigned bits = tf_bits32(hc.ck0, hc.ck1, jbase + (unsigned)c);
        const float u = __uint_as_float((bits >> 9) | 0x3f800000u) - 1.0f;
        float val = u + 1.17549435e-38f;
        val = fmaxf(val, 1.17549435e-38f);
        const float g = -logf(-logf(val));
        const float sc = lg[c] + g;
        if (sc > best) { best = sc; bc = c; }   // strict > keeps first max
      }
      const int nt = bc < (TN - 1) ? bc : (TN - 1);
      tempers[token] = nt;
      if (bc == TN) done[token] = 1;
      else atomicAdd(&lcnt[nt], 1);
    }
  }
  __syncthreads();
  if (tid < TN && lcnt[tid] > 0) atomicAdd(&cnt_next[tid], lcnt[tid]);
}

// pred = states @ pred_W + pred_b; err = mean((pred-x)^2). Wave per token.
__global__ __launch_bounds__(TPB, 2) void k_pred(
    const float* __restrict__ states, const float* __restrict__ x,
    const float* __restrict__ pW, const float* __restrict__ pb,
    float* __restrict__ pred, float* __restrict__ err)
{
  const int tid = threadIdx.x;
  const int lane = tid & 63;
  int n = blockIdx.x * 4 + (tid >> 6);
  n = __builtin_amdgcn_readfirstlane(n);
  const float* srow = states + (size_t)n * HD;
  float a0 = pb[lane], a1 = pb[64 + lane];
  for (int h = 0; h < HD; ++h) {
    const float sh = srow[h];                       // wave-uniform -> s_load
    a0 = fmaf(sh, pW[h * DIN + lane], a0);
    a1 = fmaf(sh, pW[h * DIN + 64 + lane], a1);
  }
  pred[(size_t)n * DIN + lane] = a0;
  pred[(size_t)n * DIN + 64 + lane] = a1;
  const float x0v = x[(size_t)n * DIN + lane];
  const float x1v = x[(size_t)n * DIN + 64 + lane];
  const float d0 = a0 - x0v, d1 = a1 - x1v;
  float s = fmaf(d0, d0, d1 * d1);
  #pragma unroll
  for (int off = 32; off > 0; off >>= 1) s += __shfl_xor(s, off, 64);
  if (lane == 0) err[n] = s * (1.0f / 128.0f);
}

// ---- host-side RNG constant derivation (deterministic, capture-safe) ----
static float host_erfinv(float xf) {     // XLA ErfInv32 (Giles) polynomial
  double x = xf;
  double w = -log1p(-x * x);
  double p;
  if (w < 5.0) {
    w -= 2.5;
    p = 2.81022636e-08;          p = 3.43273939e-07 + p * w;
    p = -3.5233877e-06 + p * w;  p = -4.39150654e-06 + p * w;
    p = 0.00021858087 + p * w;   p = -0.00125372503 + p * w;
    p = -0.00417768164 + p * w;  p = 0.246640727 + p * w;
    p = 1.50140941 + p * w;
  } else {
    w = sqrt(w) - 3.0;
    p = -0.000200214257;         p = 0.000100950558 + p * w;
    p = 0.00134934322 + p * w;   p = -0.00367342844 + p * w;
    p = 0.00573950773 + p * w;   p = -0.0076224613 + p * w;
    p = 0.00943887047 + p * w;   p = 1.00167406 + p * w;
    p = 2.83297682 + p * w;
  }
  return (float)(p * x);
}

static void build_hops(HopConst* hcs) {
  const float lo = nextafterf(-1.0f, 0.0f);       // -0.99999994
  const unsigned rk0 = 0u, rk1 = 42u;             // jax.random.key(42) -> [0,42]
  for (int hop = 0; hop < NHOPS; ++hop) {
    unsigned hk0, hk1;
    tf2x32(rk0, rk1, 0u, (unsigned)hop, hk0, hk1);          // fold_in(rkey, hop)
    for (int t = 0; t < TN; ++t) {
      unsigned tk0, tk1;
      tf2x32(hk0, hk1, 0u, (unsigned)t, tk0, tk1);          // fold_in(hkey, t)
      double nrm[3];
      for (int i = 0; i < 3; ++i) {
        const unsigned bits = tf_bits32(tk0, tk1, (unsigned)i);
        unsigned ub = (bits >> 9) | 0x3f800000u;
        float f; memcpy(&f, &ub, 4);
        const float u01 = f - 1.0f;
        float val = u01 * 2.0f + lo;                        // (max-min)=2.0f exactly (RNE)
        if (val < lo) val = lo;
        const float ef = host_erfinv(val);
        nrm[i] = (double)(1.41421356f * ef);                // sqrt(2) fp32 const
      }
      const double m = fmax(nrm[0], fmax(nrm[1], nrm[2]));
      const double e0 = exp(nrm[0] - m), e1 = exp(nrm[1] - m), e2 = exp(nrm[2] - m);
      const double s = e0 + e1 + e2;
      hcs[hop].w[t][0] = (float)(e0 / s);
      hcs[hop].w[t][1] = (float)(e1 / s);
      hcs[hop].w[t][2] = (float)(e2 / s);
    }
    unsigned ck0, ck1;
    tf2x32(hk0, hk1, 0u, 10000u, ck0, ck1);                 // fold_in(hkey, 10000)
    hcs[hop].ck0 = ck0; hcs[hop].ck1 = ck1;
    hcs[hop].last_hop = (hop == NHOPS - 1) ? 1 : 0;
  }
}

extern "C" void kernel_launch(void* const* d_in, const int* in_sizes, int n_in,
                              void* d_out, int out_size, void* d_ws, size_t ws_size,
                              hipStream_t stream) {
  (void)in_sizes; (void)n_in; (void)out_size; (void)ws_size;
  const float* x    = (const float*)d_in[0];
  const float* pW   = (const float*)d_in[1];
  const float* pb   = (const float*)d_in[2];
  const float* W1   = (const float*)d_in[3];
  const float* b1   = (const float*)d_in[4];
  const float* W2   = (const float*)d_in[5];
  const float* b2   = (const float*)d_in[6];
  const float* rW1  = (const float*)d_in[7];
  const float* rb1  = (const float*)d_in[8];
  const float* rW2  = (const float*)d_in[9];
  const float* rb2  = (const float*)d_in[10];
  const float* pdW  = (const float*)d_in[11];
  const float* pdb  = (const float*)d_in[12];
  const int*   itmp = (const int*)d_in[13];

  // ws layout: [meta 1KB][tempers N][done N][compact N+TN*TOKB][states N*64]
  int* meta    = (int*)d_ws;
  int* tempers = (int*)((char*)d_ws + 1024);
  int* done    = tempers + N_TOK;
  int* compact = done + N_TOK;
  float* states = (float*)(compact + N_TOK + TN * TOKB);

  HopConst hcs[NHOPS];
  build_hops(hcs);

  hipMemsetAsync(meta, 0, 160 * sizeof(int), stream);
  k_init<<<N_TOK / TPB, TPB, 0, stream>>>(x, pW, pb, itmp, states, tempers, done, meta);
  for (int h = 0; h < NHOPS; ++h) {
    int* cnt_h = meta + h * TN;
    int* cnt_n = meta + (h + 1) * TN;
    int* cur_h = meta + 60 + h * TN;
    int* off_h = meta + 108 + h * (TN + 1);
    k_prefix<<<1, 64, 0, stream>>>(cnt_h, off_h);
    k_scatter<<<N_TOK / TPB, TPB, 0, stream>>>(tempers, done, off_h, cur_h, compact);
    k_hop<<<N_TOK / TOKB + TN, TPB_HOP, 0, stream>>>(states, tempers, done, compact, cnt_h, off_h,
        W1, b1, W2, b2, rW1, rb1, rW2, rb2, cnt_n, hcs[h]);
  }
  float* pred = (float*)d_out;
  float* errp = pred + (size_t)N_TOK * DIN;
  k_pred<<<N_TOK / 4, TPB, 0, stream>>>(states, x, pdW, pdb, pred, errp);
}

// Round 7
// 362.923 us; speedup vs baseline: 1.5993x; 1.3844x over previous
//
#include <hip/hip_runtime.h>
#include <cstring>
#include <cmath>
#include <cstdint>

#define N_TOK 65536
#define DIN 128
#define HD 64
#define TN 12
#define ON 3
#define NHOPS 4
#define TPB 256
#define TPB_HOP 512      // 8 waves; wave owns a 32x32 D-tile (2 m-tiles x 2 n-tiles)
#define TOKB 128         // tokens per k_hop block
#define NCAT 13

typedef __attribute__((ext_vector_type(8))) short short8v;     // 8 bf16 frag
typedef __attribute__((ext_vector_type(4))) float f32x4;
typedef __attribute__((ext_vector_type(4))) unsigned short ushort4v;
typedef __attribute__((ext_vector_type(8))) unsigned short ushort8v;

struct HopConst {
  float w[TN][ON];
  unsigned ck0, ck1;
  int last_hop;
};

// ---- threefry2x32 (exact JAX semantics) ----
__host__ __device__ __forceinline__ void tf2x32(unsigned k0, unsigned k1,
                                                unsigned x0, unsigned x1,
                                                unsigned& o0, unsigned& o1) {
  unsigned ks2 = k0 ^ k1 ^ 0x1BD11BDAu;
  x0 += k0; x1 += k1;
#define TFR(r) { x0 += x1; x1 = (x1 << (r)) | (x1 >> (32 - (r))); x1 ^= x0; }
  TFR(13) TFR(15) TFR(26) TFR(6)
  x0 += k1;  x1 += ks2 + 1u;
  TFR(17) TFR(29) TFR(16) TFR(24)
  x0 += ks2; x1 += k0 + 2u;
  TFR(13) TFR(15) TFR(26) TFR(6)
  x0 += k0;  x1 += k1 + 3u;
  TFR(17) TFR(29) TFR(16) TFR(24)
  x0 += k1;  x1 += ks2 + 4u;
  TFR(13) TFR(15) TFR(26) TFR(6)
  x0 += ks2; x1 += k0 + 5u;
#undef TFR
  o0 = x0; o1 = x1;
}
__host__ __device__ __forceinline__ unsigned tf_bits32(unsigned k0, unsigned k1, unsigned j) {
  unsigned o0, o1;
  tf2x32(k0, k1, 0u, j, o0, o1);
  return o0 ^ o1;
}

// ---- bf16x3 splitting ----
__host__ __device__ __forceinline__ unsigned short bf16r(float v) {
  unsigned u = __builtin_bit_cast(unsigned, v);
  return (unsigned short)((u + 0x7fffu + ((u >> 16) & 1u)) >> 16);
}
__host__ __device__ __forceinline__ float bf2f(unsigned short s) {
  return __builtin_bit_cast(float, ((unsigned)s) << 16);
}
__host__ __device__ __forceinline__ void split3(float v, unsigned short& a,
                                                unsigned short& b, unsigned short& c) {
  a = bf16r(v); float r = v - bf2f(a);
  b = bf16r(r); r -= bf2f(b);
  c = bf16r(r);
}

// ---- kernels ----

__global__ __launch_bounds__(TPB, 2) void k_init(
    const float* __restrict__ x, const float* __restrict__ pW,
    const float* __restrict__ pb, const int* __restrict__ itemp,
    float* __restrict__ states, int* __restrict__ tempers,
    int* __restrict__ done, int* __restrict__ cnt0)
{
  __shared__ int lcnt[TN];
  const int tid = threadIdx.x;
  if (tid < TN) lcnt[tid] = 0;
  __syncthreads();
  const int n = blockIdx.x * TPB + tid;
  float acc[HD];
  #pragma unroll
  for (int k = 0; k < HD; ++k) acc[k] = pb[k];
  const float* xrow = x + (size_t)n * DIN;
  for (int d4 = 0; d4 < DIN / 4; ++d4) {
    const float4 xv = *(const float4*)(xrow + d4 * 4);
    const float xs[4] = {xv.x, xv.y, xv.z, xv.w};
    #pragma unroll
    for (int dd = 0; dd < 4; ++dd) {
      const float* wr = pW + (d4 * 4 + dd) * HD;
      #pragma unroll
      for (int k = 0; k < HD; ++k) acc[k] = fmaf(xs[dd], wr[k], acc[k]);
    }
  }
  float* srow = states + (size_t)n * HD;
  #pragma unroll
  for (int k4 = 0; k4 < HD / 4; ++k4) {
    float4 v; v.x = acc[k4*4]; v.y = acc[k4*4+1]; v.z = acc[k4*4+2]; v.w = acc[k4*4+3];
    *(float4*)(srow + k4 * 4) = v;
  }
  const int t = itemp[n];
  tempers[n] = t;
  done[n] = 0;
  atomicAdd(&lcnt[t], 1);
  __syncthreads();
  if (tid < TN && lcnt[tid] > 0) atomicAdd(&cnt0[tid], lcnt[tid]);
}

// one-time: split weights to bf16x3 and store in MFMA A-frag order.
// A-frag layout: frag(s, mtile, kc, lane) holds A[m=16*mtile+(lane&15)][k=32*kc+8*(lane>>4)+i]
// where A[m][k] = W[k][m] (W stored [h][j] row-major). Offset:
//   ((s*NMT + mtile)*2 + kc)*512 + lane*8 + i  (ushort units)
__global__ __launch_bounds__(TPB) void k_wprep(
    const float* __restrict__ W1, const float* __restrict__ W2,
    const float* __restrict__ rW1, const float* __restrict__ rW2,
    unsigned short* __restrict__ w1f, unsigned short* __restrict__ w2f,
    unsigned short* __restrict__ rw1f, unsigned short* __restrict__ rw2f)
{
  const int idx = blockIdx.x * TPB + threadIdx.x;
  const int NU1 = TN * ON * 4 * 2 * 64;   // 18432
  const int NU2 = 4 * 2 * 64;             // 512
  const int NU3 = 2 * 64;                 // 128
  if (idx < NU1) {
    const int lane = idx & 63, kc = (idx >> 6) & 1, mt = (idx >> 7) & 3, mat = idx >> 9;
    const int j = 16 * mt + (lane & 15);
    const int h0 = 32 * kc + 8 * (lane >> 4);
    const float* s1 = W1 + (size_t)mat * 4096;
    const float* s2 = W2 + (size_t)mat * 4096;
    #pragma unroll
    for (int i = 0; i < 8; ++i) {
      unsigned short a0, a1, a2;
      const size_t base = (size_t)mat * 12288 + (size_t)(mt * 2 + kc) * 512 + lane * 8 + i;
      split3(s1[(h0 + i) * 64 + j], a0, a1, a2);
      w1f[base] = a0; w1f[base + 4096] = a1; w1f[base + 8192] = a2;
      split3(s2[(h0 + i) * 64 + j], a0, a1, a2);
      w2f[base] = a0; w2f[base + 4096] = a1; w2f[base + 8192] = a2;
    }
  } else if (idx < NU1 + NU2) {
    const int u = idx - NU1;
    const int lane = u & 63, kc = (u >> 6) & 1, mt = (u >> 7) & 3;
    const int j = 16 * mt + (lane & 15);
    const int h0 = 32 * kc + 8 * (lane >> 4);
    #pragma unroll
    for (int i = 0; i < 8; ++i) {
      unsigned short a0, a1, a2;
      const size_t base = (size_t)(mt * 2 + kc) * 512 + lane * 8 + i;
      split3(rW1[(h0 + i) * 64 + j], a0, a1, a2);
      rw1f[base] = a0; rw1f[base + 4096] = a1; rw1f[base + 8192] = a2;
    }
  } else if (idx < NU1 + NU2 + NU3) {
    const int u = idx - NU1 - NU2;
    const int lane = u & 63, kc = (u >> 6) & 1;
    const int c = lane & 15;
    const int h0 = 32 * kc + 8 * (lane >> 4);
    #pragma unroll
    for (int i = 0; i < 8; ++i) {
      unsigned short a0, a1, a2;
      const float v = (c < NCAT) ? rW2[(h0 + i) * NCAT + c] : 0.0f;
      split3(v, a0, a1, a2);
      const size_t base = (size_t)kc * 512 + lane * 8 + i;
      rw2f[base] = a0; rw2f[base + 1024] = a1; rw2f[base + 2048] = a2;
    }
  }
}

__global__ void k_prefix(const int* __restrict__ cnt, int* __restrict__ offp) {
  if (threadIdx.x == 0 && blockIdx.x == 0) {
    int o = 0;
    for (int t = 0; t < TN; ++t) { offp[t] = o; o += (cnt[t] + TOKB - 1) & ~(TOKB - 1); }
    offp[TN] = o;
  }
}

__global__ __launch_bounds__(TPB) void k_scatter(
    const int* __restrict__ tempers, const int* __restrict__ done,
    const int* __restrict__ offp, int* __restrict__ cursor, int* __restrict__ compact)
{
  __shared__ int lcnt[TN], lbase[TN];
  const int tid = threadIdx.x;
  if (tid < TN) lcnt[tid] = 0;
  __syncthreads();
  const int n = blockIdx.x * TPB + tid;
  int t = -1, lpos = 0;
  if (!done[n]) { t = tempers[n]; lpos = atomicAdd(&lcnt[t], 1); }
  __syncthreads();
  if (tid < TN && lcnt[tid] > 0) lbase[tid] = atomicAdd(&cursor[tid], lcnt[tid]);
  __syncthreads();
  if (t >= 0) compact[offp[t] + lbase[t] + lpos] = n;
}

// B-frag fetch from swizzled LDS acts ([s][tok][h] bf16, 16B chunks XOR tok&7)
__device__ __forceinline__ short8v bfrag(const unsigned short* sBase, int s, int ntile,
                                         int kc, int lane) {
  const int tok = (lane & 15) + 16 * ntile;
  const int chunk = (4 * kc + (lane >> 4)) ^ (tok & 7);
  return *(const short8v*)(sBase + s * 8192 + tok * 64 + chunk * 8);
}

__device__ __forceinline__ void load_bfrags(const unsigned short* sBase, int ngrp, int lane,
                                            short8v bf[3][2][2]) {
  #pragma unroll
  for (int s = 0; s < 3; ++s)
    #pragma unroll
    for (int nt = 0; nt < 2; ++nt)
      #pragma unroll
      for (int kc = 0; kc < 2; ++kc)
        bf[s][nt][kc] = bfrag(sBase, s, 2 * ngrp + nt, kc, lane);
}

// 6-pass bf16x3 MFMA accumulate into 2x2 D-tiles
__device__ __forceinline__ void mfma_all(const unsigned short* __restrict__ Ag,
                                         const short8v bf[3][2][2],
                                         int mgrp, int lane, f32x4 acc[2][2]) {
  #pragma unroll
  for (int sw = 0; sw < 3; ++sw) {
    short8v a[2][2];
    #pragma unroll
    for (int mt = 0; mt < 2; ++mt)
      #pragma unroll
      for (int kc = 0; kc < 2; ++kc)
        a[mt][kc] = *(const short8v*)(Ag +
            (size_t)((sw * 4 + (2 * mgrp + mt)) * 2 + kc) * 512 + lane * 8);
    #pragma unroll
    for (int sa = 0; sa < 3; ++sa) {
      if (sw + sa > 2) continue;
      #pragma unroll
      for (int mt = 0; mt < 2; ++mt)
        #pragma unroll
        for (int nt = 0; nt < 2; ++nt)
          #pragma unroll
          for (int kc = 0; kc < 2; ++kc)
            acc[mt][nt] = __builtin_amdgcn_mfma_f32_16x16x32_bf16(
                a[mt][kc], bf[sa][nt][kc], acc[mt][nt], 0, 0, 0);
    }
  }
}

// bias + relu + split3 -> swizzled LDS store ([s][tok][h] bf16)
__device__ __forceinline__ void store_h1(const f32x4 acc[2][2], const float* __restrict__ bias,
                                         unsigned short* dst, int mgrp, int ngrp, int lane) {
  #pragma unroll
  for (int mt = 0; mt < 2; ++mt) {
    const int mt2 = 2 * mgrp + mt;
    const int j0 = 16 * mt2 + 4 * (lane >> 4);
    const float4 bv = *(const float4*)(bias + j0);
    const float bb[4] = {bv.x, bv.y, bv.z, bv.w};
    #pragma unroll
    for (int nt = 0; nt < 2; ++nt) {
      const int tok = (lane & 15) + 16 * (2 * ngrp + nt);
      ushort4v u0, u1, u2;
      #pragma unroll
      for (int r = 0; r < 4; ++r) {
        const float v = fmaxf(acc[mt][nt][r] + bb[r], 0.0f);
        unsigned short a, b, c;
        split3(v, a, b, c);
        u0[r] = a; u1[r] = b; u2[r] = c;
      }
      const int chunk = (2 * mt2 + ((lane >> 4) >> 1)) ^ (tok & 7);
      const int half = (lane >> 4) & 1;
      const int base = tok * 64 + chunk * 8 + half * 4;
      *(ushort4v*)(dst + base) = u0;
      *(ushort4v*)(dst + 8192 + base) = u1;
      *(ushort4v*)(dst + 16384 + base) = u2;
    }
  }
}

// main per-hop kernel: bf16x3 MFMA, weights as frag-ordered global, acts via swizzled LDS
__global__ __launch_bounds__(TPB_HOP, 2) void k_hop(
    float* __restrict__ states, int* __restrict__ tempers, int* __restrict__ done,
    const int* __restrict__ compact, const int* __restrict__ cnt,
    const int* __restrict__ offp,
    const unsigned short* __restrict__ w1f, const float* __restrict__ b1,
    const unsigned short* __restrict__ w2f, const float* __restrict__ b2,
    const unsigned short* __restrict__ rw1f, const float* __restrict__ rb1,
    const unsigned short* __restrict__ rw2f, const float* __restrict__ rb2,
    int* __restrict__ cnt_next, HopConst hc)
{
  __shared__ unsigned short sX[3 * TOKB * HD];   // 48KB acts splits / logits f32
  __shared__ unsigned short sH[3 * TOKB * HD];   // 48KB h1 splits / out f32
  __shared__ int stok[TOKB];
  __shared__ unsigned char sact[TOKB];
  __shared__ int lcnt[TN];

  const int tid = threadIdx.x;
  const int lane = tid & 63;
  const int w = __builtin_amdgcn_readfirstlane(tid >> 6);
  const int mgrp = w & 1, ngrp = w >> 1;
  const int bstart = blockIdx.x * TOKB;
  if (bstart >= offp[TN]) return;
  int tt = 0;
  #pragma unroll
  for (int i = 1; i < TN; ++i) if (bstart >= offp[i]) tt = i;
  const int t = __builtin_amdgcn_readfirstlane(tt);
  const int cntt = cnt[t];
  const int slot = tid & 127;
  const int hq = tid >> 7;

  // ---- stage states: f32 -> bf16x3 swizzled LDS ----
  {
    const int pos = bstart + slot;
    const bool a = (pos - offp[t]) < cntt;
    const int tok = compact[a ? pos : offp[t]];
    if (hq == 0) { stok[slot] = tok; sact[slot] = a ? 1 : 0; }
    const float* sr = states + (size_t)tok * HD + hq * 16;
    float v[16];
    #pragma unroll
    for (int q = 0; q < 4; ++q) {
      const float4 f = *(const float4*)(sr + q * 4);
      v[q*4] = f.x; v[q*4+1] = f.y; v[q*4+2] = f.z; v[q*4+3] = f.w;
    }
    unsigned short sp[3][16];
    #pragma unroll
    for (int i = 0; i < 16; ++i) split3(v[i], sp[0][i], sp[1][i], sp[2][i]);
    #pragma unroll
    for (int s = 0; s < 3; ++s)
      #pragma unroll
      for (int cj = 0; cj < 2; ++cj) {
        ushort8v u;
        #pragma unroll
        for (int i = 0; i < 8; ++i) u[i] = sp[s][cj * 8 + i];
        const int chunk = (2 * hq + cj) ^ (slot & 7);
        *(ushort8v*)(sX + s * 8192 + slot * 64 + chunk * 8) = u;
      }
  }
  if (tid < TN) lcnt[tid] = 0;
  __syncthreads();

  const f32x4 zf = {0.0f, 0.0f, 0.0f, 0.0f};
  f32x4 out[2][2] = {{zf, zf}, {zf, zf}};

  #pragma unroll 1
  for (int o = 0; o < ON; ++o) {
    const int mat = t * ON + o;
    // L1
    short8v bf[3][2][2];
    load_bfrags(sX, ngrp, lane, bf);
    f32x4 acc[2][2] = {{zf, zf}, {zf, zf}};
    mfma_all(w1f + (size_t)mat * 12288, bf, mgrp, lane, acc);
    __syncthreads();                         // prev L2 readers of sH done
    store_h1(acc, b1 + mat * 64, sH, mgrp, ngrp, lane);
    __syncthreads();                         // h1 splits visible
    // L2
    load_bfrags(sH, ngrp, lane, bf);
    f32x4 acc2[2][2] = {{zf, zf}, {zf, zf}};
    mfma_all(w2f + (size_t)mat * 12288, bf, mgrp, lane, acc2);
    const float wo = hc.w[t][o];
    #pragma unroll
    for (int mt = 0; mt < 2; ++mt) {
      const int j0 = 16 * (2 * mgrp + mt) + 4 * (lane >> 4);
      const float4 bv = *(const float4*)(b2 + mat * 64 + j0);
      const float bb[4] = {bv.x, bv.y, bv.z, bv.w};
      #pragma unroll
      for (int nt = 0; nt < 2; ++nt)
        #pragma unroll
        for (int r = 0; r < 4; ++r)
          out[mt][nt][r] = fmaf(wo, fmaxf(acc2[mt][nt][r] + bb[r], 0.0f), out[mt][nt][r]);
    }
  }
  __syncthreads();                           // all sH/sX reads done

  // ---- out: f32 -> sH (swizzled f32) ; splits -> sX for routing ----
  float* sHf = (float*)sH;
  #pragma unroll
  for (int mt = 0; mt < 2; ++mt) {
    const int mt2 = 2 * mgrp + mt;
    #pragma unroll
    for (int nt = 0; nt < 2; ++nt) {
      const int tok = (lane & 15) + 16 * (2 * ngrp + nt);
      const int chunk = (4 * mt2 + (lane >> 4)) ^ (tok & 15);
      *(f32x4*)(sHf + tok * 64 + chunk * 4) = out[mt][nt];
    }
  }
  if (!hc.last_hop) {
    #pragma unroll
    for (int mt = 0; mt < 2; ++mt) {
      const int mt2 = 2 * mgrp + mt;
      #pragma unroll
      for (int nt = 0; nt < 2; ++nt) {
        const int tok = (lane & 15) + 16 * (2 * ngrp + nt);
        ushort4v u0, u1, u2;
        #pragma unroll
        for (int r = 0; r < 4; ++r) {
          unsigned short a, b, c;
          split3(out[mt][nt][r], a, b, c);
          u0[r] = a; u1[r] = b; u2[r] = c;
        }
        const int chunk = (2 * mt2 + ((lane >> 4) >> 1)) ^ (tok & 7);
        const int half = (lane >> 4) & 1;
        const int base = tok * 64 + chunk * 8 + half * 4;
        *(ushort4v*)(sX + base) = u0;
        *(ushort4v*)(sX + 8192 + base) = u1;
        *(ushort4v*)(sX + 16384 + base) = u2;
      }
    }
  }
  __syncthreads();                           // out f32 + splits visible

  // ---- coalesced states write-back from sHf ----
  if (sact[slot]) {
    float* wr = states + (size_t)stok[slot] * HD + hq * 16;
    #pragma unroll
    for (int cc = 0; cc < 4; ++cc) {
      const int chunk = (4 * hq + cc) ^ (slot & 15);
      *(float4*)(wr + cc * 4) = *(const float4*)(sHf + slot * 64 + chunk * 4);
    }
  }
  if (hc.last_hop) return;

  // ---- r1 = relu(out @ rW1 + rb1) ----
  {
    short8v bf[3][2][2];
    load_bfrags(sX, ngrp, lane, bf);
    f32x4 acc[2][2] = {{zf, zf}, {zf, zf}};
    mfma_all(rw1f, bf, mgrp, lane, acc);
    __syncthreads();                         // write-back reads of sHf done
    store_h1(acc, rb1, sH, mgrp, ngrp, lane);
  }
  __syncthreads();                           // r1 splits visible

  // ---- logits = r1 @ rW2 (wave w owns n-tile w); bias added in sampler ----
  {
    short8v bfr[3][2];
    #pragma unroll
    for (int s = 0; s < 3; ++s)
      #pragma unroll
      for (int kc = 0; kc < 2; ++kc)
        bfr[s][kc] = bfrag(sH, s, w, kc, lane);
    f32x4 acc = zf;
    #pragma unroll
    for (int sw = 0; sw < 3; ++sw) {
      short8v a[2];
      #pragma unroll
      for (int kc = 0; kc < 2; ++kc)
        a[kc] = *(const short8v*)(rw2f + (size_t)(sw * 2 + kc) * 512 + lane * 8);
      #pragma unroll
      for (int sa = 0; sa < 3; ++sa) {
        if (sw + sa > 2) continue;
        #pragma unroll
        for (int kc = 0; kc < 2; ++kc)
          acc = __builtin_amdgcn_mfma_f32_16x16x32_bf16(a[kc], bfr[sa][kc], acc, 0, 0, 0);
      }
    }
    float* sXf = (float*)sX;
    const int tok = (lane & 15) + 16 * w;
    *(f32x4*)(sXf + tok * 16 + (lane >> 4) * 4) = acc;
  }
  __syncthreads();

  // ---- gumbel-argmax sample, one thread per token ----
  if (tid < TOKB && sact[tid]) {
    const float* lrow = (const float*)sX + tid * 16;
    const int token = stok[tid];
    const unsigned jbase = (unsigned)token * (unsigned)NCAT;
    float best = -3.0e38f; int bc = 0;
    #pragma unroll
    for (int c = 0; c < NCAT; ++c) {
      const float L = lrow[c] + rb2[c];
      const unsigned bits = tf_bits32(hc.ck0, hc.ck1, jbase + (unsigned)c);
      const float u = __uint_as_float((bits >> 9) | 0x3f800000u) - 1.0f;
      float val = u + 1.17549435e-38f;
      val = fmaxf(val, 1.17549435e-38f);
      const float g = -logf(-logf(val));
      const float sc = L + g;
      if (sc > best) { best = sc; bc = c; }   // strict > keeps first max
    }
    const int nt = bc < (TN - 1) ? bc : (TN - 1);
    tempers[token] = nt;
    if (bc == TN) done[token] = 1;
    else atomicAdd(&lcnt[nt], 1);
  }
  __syncthreads();
  if (tid < TN && lcnt[tid] > 0) atomicAdd(&cnt_next[tid], lcnt[tid]);
}

// pred = states @ pred_W + pred_b; err = mean((pred-x)^2). Wave per token.
__global__ __launch_bounds__(TPB, 2) void k_pred(
    const float* __restrict__ states, const float* __restrict__ x,
    const float* __restrict__ pW, const float* __restrict__ pb,
    float* __restrict__ pred, float* __restrict__ err)
{
  const int tid = threadIdx.x;
  const int lane = tid & 63;
  int n = blockIdx.x * 4 + (tid >> 6);
  n = __builtin_amdgcn_readfirstlane(n);
  const float* srow = states + (size_t)n * HD;
  float a0 = pb[lane], a1 = pb[64 + lane];
  for (int h = 0; h < HD; ++h) {
    const float sh = srow[h];
    a0 = fmaf(sh, pW[h * DIN + lane], a0);
    a1 = fmaf(sh, pW[h * DIN + 64 + lane], a1);
  }
  pred[(size_t)n * DIN + lane] = a0;
  pred[(size_t)n * DIN + 64 + lane] = a1;
  const float x0v = x[(size_t)n * DIN + lane];
  const float x1v = x[(size_t)n * DIN + 64 + lane];
  const float d0 = a0 - x0v, d1 = a1 - x1v;
  float s = fmaf(d0, d0, d1 * d1);
  #pragma unroll
  for (int off = 32; off > 0; off >>= 1) s += __shfl_xor(s, off, 64);
  if (lane == 0) err[n] = s * (1.0f / 128.0f);
}

// ---- host-side RNG constant derivation ----
static float host_erfinv(float xf) {
  double x = xf;
  double w = -log1p(-x * x);
  double p;
  if (w < 5.0) {
    w -= 2.5;
    p = 2.81022636e-08;          p = 3.43273939e-07 + p * w;
    p = -3.5233877e-06 + p * w;  p = -4.39150654e-06 + p * w;
    p = 0.00021858087 + p * w;   p = -0.00125372503 + p * w;
    p = -0.00417768164 + p * w;  p = 0.246640727 + p * w;
    p = 1.50140941 + p * w;
  } else {
    w = sqrt(w) - 3.0;
    p = -0.000200214257;         p = 0.000100950558 + p * w;
    p = 0.00134934322 + p * w;   p = -0.00367342844 + p * w;
    p = 0.00573950773 + p * w;   p = -0.0076224613 + p * w;
    p = 0.00943887047 + p * w;   p = 1.00167406 + p * w;
    p = 2.83297682 + p * w;
  }
  return (float)(p * x);
}

static void build_hops(HopConst* hcs) {
  const float lo = nextafterf(-1.0f, 0.0f);
  const unsigned rk0 = 0u, rk1 = 42u;
  for (int hop = 0; hop < NHOPS; ++hop) {
    unsigned hk0, hk1;
    tf2x32(rk0, rk1, 0u, (unsigned)hop, hk0, hk1);
    for (int t = 0; t < TN; ++t) {
      unsigned tk0, tk1;
      tf2x32(hk0, hk1, 0u, (unsigned)t, tk0, tk1);
      double nrm[3];
      for (int i = 0; i < 3; ++i) {
        const unsigned bits = tf_bits32(tk0, tk1, (unsigned)i);
        unsigned ub = (bits >> 9) | 0x3f800000u;
        float f; memcpy(&f, &ub, 4);
        const float u01 = f - 1.0f;
        float val = u01 * 2.0f + lo;
        if (val < lo) val = lo;
        const float ef = host_erfinv(val);
        nrm[i] = (double)(1.41421356f * ef);
      }
      const double m = fmax(nrm[0], fmax(nrm[1], nrm[2]));
      const double e0 = exp(nrm[0] - m), e1 = exp(nrm[1] - m), e2 = exp(nrm[2] - m);
      const double s = e0 + e1 + e2;
      hcs[hop].w[t][0] = (float)(e0 / s);
      hcs[hop].w[t][1] = (float)(e1 / s);
      hcs[hop].w[t][2] = (float)(e2 / s);
    }
    unsigned ck0, ck1;
    tf2x32(hk0, hk1, 0u, 10000u, ck0, ck1);
    hcs[hop].ck0 = ck0; hcs[hop].ck1 = ck1;
    hcs[hop].last_hop = (hop == NHOPS - 1) ? 1 : 0;
  }
}

extern "C" void kernel_launch(void* const* d_in, const int* in_sizes, int n_in,
                              void* d_out, int out_size, void* d_ws, size_t ws_size,
                              hipStream_t stream) {
  (void)in_sizes; (void)n_in; (void)out_size; (void)ws_size;
  const float* x    = (const float*)d_in[0];
  const float* pW   = (const float*)d_in[1];
  const float* pb   = (const float*)d_in[2];
  const float* W1   = (const float*)d_in[3];
  const float* b1   = (const float*)d_in[4];
  const float* W2   = (const float*)d_in[5];
  const float* b2   = (const float*)d_in[6];
  const float* rW1  = (const float*)d_in[7];
  const float* rb1  = (const float*)d_in[8];
  const float* rW2  = (const float*)d_in[9];
  const float* rb2  = (const float*)d_in[10];
  const float* pdW  = (const float*)d_in[11];
  const float* pdb  = (const float*)d_in[12];
  const int*   itmp = (const int*)d_in[13];

  // ws: [meta 1KB][tempers N][done N][compact N+TN*TOKB][states N*64 f32]
  //     [w1f 36*12288 u16][w2f 36*12288][rw1f 12288][rw2f 3072]
  int* meta    = (int*)d_ws;
  int* tempers = (int*)((char*)d_ws + 1024);
  int* done    = tempers + N_TOK;
  int* compact = done + N_TOK;
  float* states = (float*)(compact + N_TOK + TN * TOKB);
  unsigned short* w1f  = (unsigned short*)(states + (size_t)N_TOK * HD);
  unsigned short* w2f  = w1f + (size_t)TN * ON * 12288;
  unsigned short* rw1f = w2f + (size_t)TN * ON * 12288;
  unsigned short* rw2f = rw1f + 12288;

  HopConst hcs[NHOPS];
  build_hops(hcs);

  hipMemsetAsync(meta, 0, 160 * sizeof(int), stream);
  k_wprep<<<75, TPB, 0, stream>>>(W1, W2, rW1, rW2, w1f, w2f, rw1f, rw2f);
  k_init<<<N_TOK / TPB, TPB, 0, stream>>>(x, pW, pb, itmp, states, tempers, done, meta);
  for (int h = 0; h < NHOPS; ++h) {
    int* cnt_h = meta + h * TN;
    int* cnt_n = meta + (h + 1) * TN;
    int* cur_h = meta + 60 + h * TN;
    int* off_h = meta + 108 + h * (TN + 1);
    k_prefix<<<1, 64, 0, stream>>>(cnt_h, off_h);
    k_scatter<<<N_TOK / TPB, TPB, 0, stream>>>(tempers, done, off_h, cur_h, compact);
    k_hop<<<N_TOK / TOKB + TN, TPB_HOP, 0, stream>>>(states, tempers, done, compact, cnt_h, off_h,
        w1f, b1, w2f, b2, rw1f, rb1, rw2f, rb2, cnt_n, hcs[h]);
  }
  float* pred = (float*)d_out;
  float* errp = pred + (size_t)N_TOK * DIN;
  k_pred<<<N_TOK / 4, TPB, 0, stream>>>(states, x, pdW, pdb, pred, errp);
}

// Round 8
// 332.756 us; speedup vs baseline: 1.7443x; 1.0907x over previous
//
#include <hip/hip_runtime.h>
#include <cstring>
#include <cmath>
#include <cstdint>

#define N_TOK 65536
#define DIN 128
#define HD 64
#define TN 12
#define ON 3
#define NHOPS 4
#define TPB 256
#define TPB_HOP 512      // 8 waves; wave owns a 32x16 D-tile (2 m-tiles x 1 n-tile)
#define TOKB 64          // tokens per k_hop block (48KB LDS -> 3 blocks/CU)
#define NCAT 13

typedef __attribute__((ext_vector_type(8))) short short8v;     // 8 bf16 frag
typedef __attribute__((ext_vector_type(4))) float f32x4;
typedef __attribute__((ext_vector_type(4))) unsigned short ushort4v;
typedef __attribute__((ext_vector_type(8))) unsigned short ushort8v;

struct HopConst {
  float w[TN][ON];
  unsigned ck0, ck1;
  int last_hop;
};

// ---- threefry2x32 (exact JAX semantics) ----
__host__ __device__ __forceinline__ void tf2x32(unsigned k0, unsigned k1,
                                                unsigned x0, unsigned x1,
                                                unsigned& o0, unsigned& o1) {
  unsigned ks2 = k0 ^ k1 ^ 0x1BD11BDAu;
  x0 += k0; x1 += k1;
#define TFR(r) { x0 += x1; x1 = (x1 << (r)) | (x1 >> (32 - (r))); x1 ^= x0; }
  TFR(13) TFR(15) TFR(26) TFR(6)
  x0 += k1;  x1 += ks2 + 1u;
  TFR(17) TFR(29) TFR(16) TFR(24)
  x0 += ks2; x1 += k0 + 2u;
  TFR(13) TFR(15) TFR(26) TFR(6)
  x0 += k0;  x1 += k1 + 3u;
  TFR(17) TFR(29) TFR(16) TFR(24)
  x0 += k1;  x1 += ks2 + 4u;
  TFR(13) TFR(15) TFR(26) TFR(6)
  x0 += ks2; x1 += k0 + 5u;
#undef TFR
  o0 = x0; o1 = x1;
}
__host__ __device__ __forceinline__ unsigned tf_bits32(unsigned k0, unsigned k1, unsigned j) {
  unsigned o0, o1;
  tf2x32(k0, k1, 0u, j, o0, o1);
  return o0 ^ o1;
}

// ---- bf16x3 splitting ----
__host__ __device__ __forceinline__ unsigned short bf16r(float v) {
  unsigned u = __builtin_bit_cast(unsigned, v);
  return (unsigned short)((u + 0x7fffu + ((u >> 16) & 1u)) >> 16);
}
__host__ __device__ __forceinline__ float bf2f(unsigned short s) {
  return __builtin_bit_cast(float, ((unsigned)s) << 16);
}
__host__ __device__ __forceinline__ void split3(float v, unsigned short& a,
                                                unsigned short& b, unsigned short& c) {
  a = bf16r(v); float r = v - bf2f(a);
  b = bf16r(r); r -= bf2f(b);
  c = bf16r(r);
}

// ---- kernels ----

__global__ __launch_bounds__(TPB, 2) void k_init(
    const float* __restrict__ x, const float* __restrict__ pW,
    const float* __restrict__ pb, const int* __restrict__ itemp,
    float* __restrict__ states, int* __restrict__ tempers,
    int* __restrict__ done, int* __restrict__ cnt0)
{
  __shared__ int lcnt[TN];
  const int tid = threadIdx.x;
  if (tid < TN) lcnt[tid] = 0;
  __syncthreads();
  const int n = blockIdx.x * TPB + tid;
  float acc[HD];
  #pragma unroll
  for (int k = 0; k < HD; ++k) acc[k] = pb[k];
  const float* xrow = x + (size_t)n * DIN;
  for (int d4 = 0; d4 < DIN / 4; ++d4) {
    const float4 xv = *(const float4*)(xrow + d4 * 4);
    const float xs[4] = {xv.x, xv.y, xv.z, xv.w};
    #pragma unroll
    for (int dd = 0; dd < 4; ++dd) {
      const float* wr = pW + (d4 * 4 + dd) * HD;
      #pragma unroll
      for (int k = 0; k < HD; ++k) acc[k] = fmaf(xs[dd], wr[k], acc[k]);
    }
  }
  float* srow = states + (size_t)n * HD;
  #pragma unroll
  for (int k4 = 0; k4 < HD / 4; ++k4) {
    float4 v; v.x = acc[k4*4]; v.y = acc[k4*4+1]; v.z = acc[k4*4+2]; v.w = acc[k4*4+3];
    *(float4*)(srow + k4 * 4) = v;
  }
  const int t = itemp[n];
  tempers[n] = t;
  done[n] = 0;
  atomicAdd(&lcnt[t], 1);
  __syncthreads();
  if (tid < TN && lcnt[tid] > 0) atomicAdd(&cnt0[tid], lcnt[tid]);
}

// one-time: split weights to bf16x3 and store in MFMA A-frag order.
// A-frag layout: frag(s, mtile, kc, lane) holds A[m=16*mtile+(lane&15)][k=32*kc+8*(lane>>4)+i]
// where A[m][k] = W[k][m] (W stored [h][j] row-major). Offset:
//   ((s*NMT + mtile)*2 + kc)*512 + lane*8 + i  (ushort units)
__global__ __launch_bounds__(TPB) void k_wprep(
    const float* __restrict__ W1, const float* __restrict__ W2,
    const float* __restrict__ rW1, const float* __restrict__ rW2,
    unsigned short* __restrict__ w1f, unsigned short* __restrict__ w2f,
    unsigned short* __restrict__ rw1f, unsigned short* __restrict__ rw2f)
{
  const int idx = blockIdx.x * TPB + threadIdx.x;
  const int NU1 = TN * ON * 4 * 2 * 64;   // 18432
  const int NU2 = 4 * 2 * 64;             // 512
  const int NU3 = 2 * 64;                 // 128
  if (idx < NU1) {
    const int lane = idx & 63, kc = (idx >> 6) & 1, mt = (idx >> 7) & 3, mat = idx >> 9;
    const int j = 16 * mt + (lane & 15);
    const int h0 = 32 * kc + 8 * (lane >> 4);
    const float* s1 = W1 + (size_t)mat * 4096;
    const float* s2 = W2 + (size_t)mat * 4096;
    #pragma unroll
    for (int i = 0; i < 8; ++i) {
      unsigned short a0, a1, a2;
      const size_t base = (size_t)mat * 12288 + (size_t)(mt * 2 + kc) * 512 + lane * 8 + i;
      split3(s1[(h0 + i) * 64 + j], a0, a1, a2);
      w1f[base] = a0; w1f[base + 4096] = a1; w1f[base + 8192] = a2;
      split3(s2[(h0 + i) * 64 + j], a0, a1, a2);
      w2f[base] = a0; w2f[base + 4096] = a1; w2f[base + 8192] = a2;
    }
  } else if (idx < NU1 + NU2) {
    const int u = idx - NU1;
    const int lane = u & 63, kc = (u >> 6) & 1, mt = (u >> 7) & 3;
    const int j = 16 * mt + (lane & 15);
    const int h0 = 32 * kc + 8 * (lane >> 4);
    #pragma unroll
    for (int i = 0; i < 8; ++i) {
      unsigned short a0, a1, a2;
      const size_t base = (size_t)(mt * 2 + kc) * 512 + lane * 8 + i;
      split3(rW1[(h0 + i) * 64 + j], a0, a1, a2);
      rw1f[base] = a0; rw1f[base + 4096] = a1; rw1f[base + 8192] = a2;
    }
  } else if (idx < NU1 + NU2 + NU3) {
    const int u = idx - NU1 - NU2;
    const int lane = u & 63, kc = (u >> 6) & 1;
    const int c = lane & 15;
    const int h0 = 32 * kc + 8 * (lane >> 4);
    #pragma unroll
    for (int i = 0; i < 8; ++i) {
      unsigned short a0, a1, a2;
      const float v = (c < NCAT) ? rW2[(h0 + i) * NCAT + c] : 0.0f;
      split3(v, a0, a1, a2);
      const size_t base = (size_t)kc * 512 + lane * 8 + i;
      rw2f[base] = a0; rw2f[base + 1024] = a1; rw2f[base + 2048] = a2;
    }
  }
}

__global__ void k_prefix(const int* __restrict__ cnt, int* __restrict__ offp) {
  if (threadIdx.x == 0 && blockIdx.x == 0) {
    int o = 0;
    for (int t = 0; t < TN; ++t) { offp[t] = o; o += (cnt[t] + TOKB - 1) & ~(TOKB - 1); }
    offp[TN] = o;
  }
}

__global__ __launch_bounds__(TPB) void k_scatter(
    const int* __restrict__ tempers, const int* __restrict__ done,
    const int* __restrict__ offp, int* __restrict__ cursor, int* __restrict__ compact)
{
  __shared__ int lcnt[TN], lbase[TN];
  const int tid = threadIdx.x;
  if (tid < TN) lcnt[tid] = 0;
  __syncthreads();
  const int n = blockIdx.x * TPB + tid;
  int t = -1, lpos = 0;
  if (!done[n]) { t = tempers[n]; lpos = atomicAdd(&lcnt[t], 1); }
  __syncthreads();
  if (tid < TN && lcnt[tid] > 0) lbase[tid] = atomicAdd(&cursor[tid], lcnt[tid]);
  __syncthreads();
  if (t >= 0) compact[offp[t] + lbase[t] + lpos] = n;
}

// B-frag fetch from swizzled LDS acts ([s][tok][h] bf16, 16B chunks XOR tok&7)
__device__ __forceinline__ short8v bfrag(const unsigned short* sBase, int s, int ntile,
                                         int kc, int lane) {
  const int tok = (lane & 15) + 16 * ntile;
  const int chunk = (4 * kc + (lane >> 4)) ^ (tok & 7);
  return *(const short8v*)(sBase + s * 4096 + tok * 64 + chunk * 8);
}

__device__ __forceinline__ void load_bfrags(const unsigned short* sBase, int ngrp, int lane,
                                            short8v bf[3][2]) {
  #pragma unroll
  for (int s = 0; s < 3; ++s)
    #pragma unroll
    for (int kc = 0; kc < 2; ++kc)
      bf[s][kc] = bfrag(sBase, s, ngrp, kc, lane);
}

// 6-pass bf16x3 MFMA accumulate into 2 D-tiles (mt), single n-tile
__device__ __forceinline__ void mfma_all(const unsigned short* __restrict__ Ag,
                                         const short8v bf[3][2],
                                         int mgrp, int lane, f32x4 acc[2]) {
  #pragma unroll
  for (int sw = 0; sw < 3; ++sw) {
    short8v a[2][2];
    #pragma unroll
    for (int mt = 0; mt < 2; ++mt)
      #pragma unroll
      for (int kc = 0; kc < 2; ++kc)
        a[mt][kc] = *(const short8v*)(Ag +
            (size_t)((sw * 4 + (2 * mgrp + mt)) * 2 + kc) * 512 + lane * 8);
    #pragma unroll
    for (int sa = 0; sa < 3; ++sa) {
      if (sw + sa > 2) continue;
      #pragma unroll
      for (int mt = 0; mt < 2; ++mt)
        #pragma unroll
        for (int kc = 0; kc < 2; ++kc)
          acc[mt] = __builtin_amdgcn_mfma_f32_16x16x32_bf16(
              a[mt][kc], bf[sa][kc], acc[mt], 0, 0, 0);
    }
  }
}

// bias + relu + split3 -> swizzled LDS store ([s][tok][h] bf16)
__device__ __forceinline__ void store_h1(const f32x4 acc[2], const float* __restrict__ bias,
                                         unsigned short* dst, int mgrp, int ngrp, int lane) {
  const int tok = (lane & 15) + 16 * ngrp;
  #pragma unroll
  for (int mt = 0; mt < 2; ++mt) {
    const int mt2 = 2 * mgrp + mt;
    const int j0 = 16 * mt2 + 4 * (lane >> 4);
    const float4 bv = *(const float4*)(bias + j0);
    const float bb[4] = {bv.x, bv.y, bv.z, bv.w};
    ushort4v u0, u1, u2;
    #pragma unroll
    for (int r = 0; r < 4; ++r) {
      const float v = fmaxf(acc[mt][r] + bb[r], 0.0f);
      unsigned short a, b, c;
      split3(v, a, b, c);
      u0[r] = a; u1[r] = b; u2[r] = c;
    }
    const int chunk = (2 * mt2 + ((lane >> 4) >> 1)) ^ (tok & 7);
    const int half = (lane >> 4) & 1;
    const int base = tok * 64 + chunk * 8 + half * 4;
    *(ushort4v*)(dst + base) = u0;
    *(ushort4v*)(dst + 4096 + base) = u1;
    *(ushort4v*)(dst + 8192 + base) = u2;
  }
}

// main per-hop kernel: bf16x3 MFMA, weights frag-ordered global (L2-hot),
// acts via swizzled LDS. 48KB LDS -> 3 blocks/CU co-resident.
__global__ __launch_bounds__(TPB_HOP, 6) void k_hop(
    float* __restrict__ states, int* __restrict__ tempers, int* __restrict__ done,
    const int* __restrict__ compact, const int* __restrict__ cnt,
    const int* __restrict__ offp,
    const unsigned short* __restrict__ w1f, const float* __restrict__ b1,
    const unsigned short* __restrict__ w2f, const float* __restrict__ b2,
    const unsigned short* __restrict__ rw1f, const float* __restrict__ rb1,
    const unsigned short* __restrict__ rw2f, const float* __restrict__ rb2,
    int* __restrict__ cnt_next, HopConst hc)
{
  __shared__ unsigned short sX[3 * TOKB * HD];   // 24KB acts splits / logits f32
  __shared__ unsigned short sH[3 * TOKB * HD];   // 24KB h1 splits / out f32
  __shared__ int stok[TOKB];
  __shared__ unsigned char sact[TOKB];
  __shared__ int lcnt[TN];

  const int tid = threadIdx.x;
  const int lane = tid & 63;
  const int w = __builtin_amdgcn_readfirstlane(tid >> 6);
  const int mgrp = w & 1, ngrp = w >> 1;          // 2 feat-halves x 4 tok-quarters
  const int bstart = blockIdx.x * TOKB;
  if (bstart >= offp[TN]) return;
  int tt = 0;
  #pragma unroll
  for (int i = 1; i < TN; ++i) if (bstart >= offp[i]) tt = i;
  const int t = __builtin_amdgcn_readfirstlane(tt);
  const int cntt = cnt[t];
  const int slot = tid & 63;
  const int hq = tid >> 6;                        // 8 h-values per thread

  // ---- stage states: f32 -> bf16x3 swizzled LDS ----
  {
    const int pos = bstart + slot;
    const bool a = (pos - offp[t]) < cntt;
    const int tok = compact[a ? pos : offp[t]];
    if (hq == 0) { stok[slot] = tok; sact[slot] = a ? 1 : 0; }
    const float* sr = states + (size_t)tok * HD + hq * 8;
    float v[8];
    #pragma unroll
    for (int q = 0; q < 2; ++q) {
      const float4 f = *(const float4*)(sr + q * 4);
      v[q*4] = f.x; v[q*4+1] = f.y; v[q*4+2] = f.z; v[q*4+3] = f.w;
    }
    unsigned short sp[3][8];
    #pragma unroll
    for (int i = 0; i < 8; ++i) split3(v[i], sp[0][i], sp[1][i], sp[2][i]);
    const int chunk = hq ^ (slot & 7);
    #pragma unroll
    for (int s = 0; s < 3; ++s) {
      ushort8v u;
      #pragma unroll
      for (int i = 0; i < 8; ++i) u[i] = sp[s][i];
      *(ushort8v*)(sX + s * 4096 + slot * 64 + chunk * 8) = u;
    }
  }
  if (tid < TN) lcnt[tid] = 0;
  __syncthreads();

  const f32x4 zf = {0.0f, 0.0f, 0.0f, 0.0f};
  f32x4 out[2] = {zf, zf};

  #pragma unroll 1
  for (int o = 0; o < ON; ++o) {
    const int mat = t * ON + o;
    // L1
    short8v bf[3][2];
    load_bfrags(sX, ngrp, lane, bf);
    f32x4 acc[2] = {zf, zf};
    mfma_all(w1f + (size_t)mat * 12288, bf, mgrp, lane, acc);
    __syncthreads();                         // prev L2 readers of sH done
    store_h1(acc, b1 + mat * 64, sH, mgrp, ngrp, lane);
    __syncthreads();                         // h1 splits visible
    // L2
    load_bfrags(sH, ngrp, lane, bf);
    f32x4 acc2[2] = {zf, zf};
    mfma_all(w2f + (size_t)mat * 12288, bf, mgrp, lane, acc2);
    const float wo = hc.w[t][o];
    #pragma unroll
    for (int mt = 0; mt < 2; ++mt) {
      const int j0 = 16 * (2 * mgrp + mt) + 4 * (lane >> 4);
      const float4 bv = *(const float4*)(b2 + mat * 64 + j0);
      const float bb[4] = {bv.x, bv.y, bv.z, bv.w};
      #pragma unroll
      for (int r = 0; r < 4; ++r)
        out[mt][r] = fmaf(wo, fmaxf(acc2[mt][r] + bb[r], 0.0f), out[mt][r]);
    }
  }
  __syncthreads();                           // all sH/sX reads done

  // ---- out: f32 -> sH (swizzled f32) ; splits -> sX for routing ----
  float* sHf = (float*)sH;
  {
    const int tok = (lane & 15) + 16 * ngrp;
    #pragma unroll
    for (int mt = 0; mt < 2; ++mt) {
      const int mt2 = 2 * mgrp + mt;
      const int chunk = (4 * mt2 + (lane >> 4)) ^ (tok & 15);
      *(f32x4*)(sHf + tok * 64 + chunk * 4) = out[mt];
    }
    if (!hc.last_hop) {
      #pragma unroll
      for (int mt = 0; mt < 2; ++mt) {
        const int mt2 = 2 * mgrp + mt;
        ushort4v u0, u1, u2;
        #pragma unroll
        for (int r = 0; r < 4; ++r) {
          unsigned short a, b, c;
          split3(out[mt][r], a, b, c);
          u0[r] = a; u1[r] = b; u2[r] = c;
        }
        const int chunk = (2 * mt2 + ((lane >> 4) >> 1)) ^ (tok & 7);
        const int half = (lane >> 4) & 1;
        const int base = tok * 64 + chunk * 8 + half * 4;
        *(ushort4v*)(sX + base) = u0;
        *(ushort4v*)(sX + 4096 + base) = u1;
        *(ushort4v*)(sX + 8192 + base) = u2;
      }
    }
  }
  __syncthreads();                           // out f32 + splits visible

  // ---- coalesced states write-back from sHf ----
  if (sact[slot]) {
    float* wr = states + (size_t)stok[slot] * HD + hq * 8;
    #pragma unroll
    for (int cc = 0; cc < 2; ++cc) {
      const int chunk = (2 * hq + cc) ^ (slot & 15);
      *(float4*)(wr + cc * 4) = *(const float4*)(sHf + slot * 64 + chunk * 4);
    }
  }
  if (hc.last_hop) return;

  // ---- r1 = relu(out @ rW1 + rb1) ----
  {
    short8v bf[3][2];
    load_bfrags(sX, ngrp, lane, bf);
    f32x4 acc[2] = {zf, zf};
    mfma_all(rw1f, bf, mgrp, lane, acc);
    __syncthreads();                         // write-back reads of sHf done
    store_h1(acc, rb1, sH, mgrp, ngrp, lane);
  }
  __syncthreads();                           // r1 splits visible

  // ---- logits = r1 @ rW2 (waves 0..3 own n-tiles); bias added in sampler ----
  if (w < 4) {
    short8v bfr[3][2];
    #pragma unroll
    for (int s = 0; s < 3; ++s)
      #pragma unroll
      for (int kc = 0; kc < 2; ++kc)
        bfr[s][kc] = bfrag(sH, s, w, kc, lane);
    f32x4 acc = zf;
    #pragma unroll
    for (int sw = 0; sw < 3; ++sw) {
      short8v a[2];
      #pragma unroll
      for (int kc = 0; kc < 2; ++kc)
        a[kc] = *(const short8v*)(rw2f + (size_t)(sw * 2 + kc) * 512 + lane * 8);
      #pragma unroll
      for (int sa = 0; sa < 3; ++sa) {
        if (sw + sa > 2) continue;
        #pragma unroll
        for (int kc = 0; kc < 2; ++kc)
          acc = __builtin_amdgcn_mfma_f32_16x16x32_bf16(a[kc], bfr[sa][kc], acc, 0, 0, 0);
      }
    }
    float* sXf = (float*)sX;
    const int tok = (lane & 15) + 16 * w;
    *(f32x4*)(sXf + tok * 16 + (lane >> 4) * 4) = acc;
  }
  __syncthreads();

  // ---- gumbel-argmax sample, one thread per token ----
  if (tid < TOKB && sact[tid]) {
    const float* lrow = (const float*)sX + tid * 16;
    const int token = stok[tid];
    const unsigned jbase = (unsigned)token * (unsigned)NCAT;
    float best = -3.0e38f; int bc = 0;
    #pragma unroll
    for (int c = 0; c < NCAT; ++c) {
      const float L = lrow[c] + rb2[c];
      const unsigned bits = tf_bits32(hc.ck0, hc.ck1, jbase + (unsigned)c);
      const float u = __uint_as_float((bits >> 9) | 0x3f800000u) - 1.0f;
      float val = u + 1.17549435e-38f;
      val = fmaxf(val, 1.17549435e-38f);
      const float g = -logf(-logf(val));
      const float sc = L + g;
      if (sc > best) { best = sc; bc = c; }   // strict > keeps first max
    }
    const int nt = bc < (TN - 1) ? bc : (TN - 1);
    tempers[token] = nt;
    if (bc == TN) done[token] = 1;
    else atomicAdd(&lcnt[nt], 1);
  }
  __syncthreads();
  if (tid < TN && lcnt[tid] > 0) atomicAdd(&cnt_next[tid], lcnt[tid]);
}

// pred = states @ pred_W + pred_b; err = mean((pred-x)^2). Wave per token.
__global__ __launch_bounds__(TPB, 2) void k_pred(
    const float* __restrict__ states, const float* __restrict__ x,
    const float* __restrict__ pW, const float* __restrict__ pb,
    float* __restrict__ pred, float* __restrict__ err)
{
  const int tid = threadIdx.x;
  const int lane = tid & 63;
  int n = blockIdx.x * 4 + (tid >> 6);
  n = __builtin_amdgcn_readfirstlane(n);
  const float* srow = states + (size_t)n * HD;
  float a0 = pb[lane], a1 = pb[64 + lane];
  for (int h = 0; h < HD; ++h) {
    const float sh = srow[h];
    a0 = fmaf(sh, pW[h * DIN + lane], a0);
    a1 = fmaf(sh, pW[h * DIN + 64 + lane], a1);
  }
  pred[(size_t)n * DIN + lane] = a0;
  pred[(size_t)n * DIN + 64 + lane] = a1;
  const float x0v = x[(size_t)n * DIN + lane];
  const float x1v = x[(size_t)n * DIN + 64 + lane];
  const float d0 = a0 - x0v, d1 = a1 - x1v;
  float s = fmaf(d0, d0, d1 * d1);
  #pragma unroll
  for (int off = 32; off > 0; off >>= 1) s += __shfl_xor(s, off, 64);
  if (lane == 0) err[n] = s * (1.0f / 128.0f);
}

// ---- host-side RNG constant derivation ----
static float host_erfinv(float xf) {
  double x = xf;
  double w = -log1p(-x * x);
  double p;
  if (w < 5.0) {
    w -= 2.5;
    p = 2.81022636e-08;          p = 3.43273939e-07 + p * w;
    p = -3.5233877e-06 + p * w;  p = -4.39150654e-06 + p * w;
    p = 0.00021858087 + p * w;   p = -0.00125372503 + p * w;
    p = -0.00417768164 + p * w;  p = 0.246640727 + p * w;
    p = 1.50140941 + p * w;
  } else {
    w = sqrt(w) - 3.0;
    p = -0.000200214257;         p = 0.000100950558 + p * w;
    p = 0.00134934322 + p * w;   p = -0.00367342844 + p * w;
    p = 0.00573950773 + p * w;   p = -0.0076224613 + p * w;
    p = 0.00943887047 + p * w;   p = 1.00167406 + p * w;
    p = 2.83297682 + p * w;
  }
  return (float)(p * x);
}

static void build_hops(HopConst* hcs) {
  const float lo = nextafterf(-1.0f, 0.0f);
  const unsigned rk0 = 0u, rk1 = 42u;
  for (int hop = 0; hop < NHOPS; ++hop) {
    unsigned hk0, hk1;
    tf2x32(rk0, rk1, 0u, (unsigned)hop, hk0, hk1);
    for (int t = 0; t < TN; ++t) {
      unsigned tk0, tk1;
      tf2x32(hk0, hk1, 0u, (unsigned)t, tk0, tk1);
      double nrm[3];
      for (int i = 0; i < 3; ++i) {
        const unsigned bits = tf_bits32(tk0, tk1, (unsigned)i);
        unsigned ub = (bits >> 9) | 0x3f800000u;
        float f; memcpy(&f, &ub, 4);
        const float u01 = f - 1.0f;
        float val = u01 * 2.0f + lo;
        if (val < lo) val = lo;
        const float ef = host_erfinv(val);
        nrm[i] = (double)(1.41421356f * ef);
      }
      const double m = fmax(nrm[0], fmax(nrm[1], nrm[2]));
      const double e0 = exp(nrm[0] - m), e1 = exp(nrm[1] - m), e2 = exp(nrm[2] - m);
      const double s = e0 + e1 + e2;
      hcs[hop].w[t][0] = (float)(e0 / s);
      hcs[hop].w[t][1] = (float)(e1 / s);
      hcs[hop].w[t][2] = (float)(e2 / s);
    }
    unsigned ck0, ck1;
    tf2x32(hk0, hk1, 0u, 10000u, ck0, ck1);
    hcs[hop].ck0 = ck0; hcs[hop].ck1 = ck1;
    hcs[hop].last_hop = (hop == NHOPS - 1) ? 1 : 0;
  }
}

extern "C" void kernel_launch(void* const* d_in, const int* in_sizes, int n_in,
                              void* d_out, int out_size, void* d_ws, size_t ws_size,
                              hipStream_t stream) {
  (void)in_sizes; (void)n_in; (void)out_size; (void)ws_size;
  const float* x    = (const float*)d_in[0];
  const float* pW   = (const float*)d_in[1];
  const float* pb   = (const float*)d_in[2];
  const float* W1   = (const float*)d_in[3];
  const float* b1   = (const float*)d_in[4];
  const float* W2   = (const float*)d_in[5];
  const float* b2   = (const float*)d_in[6];
  const float* rW1  = (const float*)d_in[7];
  const float* rb1  = (const float*)d_in[8];
  const float* rW2  = (const float*)d_in[9];
  const float* rb2  = (const float*)d_in[10];
  const float* pdW  = (const float*)d_in[11];
  const float* pdb  = (const float*)d_in[12];
  const int*   itmp = (const int*)d_in[13];

  // ws: [meta 1KB][tempers N][done N][compact N+TN*TOKB][states N*64 f32]
  //     [w1f 36*12288 u16][w2f 36*12288][rw1f 12288][rw2f 3072]
  int* meta    = (int*)d_ws;
  int* tempers = (int*)((char*)d_ws + 1024);
  int* done    = tempers + N_TOK;
  int* compact = done + N_TOK;
  float* states = (float*)(compact + N_TOK + TN * TOKB);
  unsigned short* w1f  = (unsigned short*)(states + (size_t)N_TOK * HD);
  unsigned short* w2f  = w1f + (size_t)TN * ON * 12288;
  unsigned short* rw1f = w2f + (size_t)TN * ON * 12288;
  unsigned short* rw2f = rw1f + 12288;

  HopConst hcs[NHOPS];
  build_hops(hcs);

  hipMemsetAsync(meta, 0, 160 * sizeof(int), stream);
  k_wprep<<<75, TPB, 0, stream>>>(W1, W2, rW1, rW2, w1f, w2f, rw1f, rw2f);
  k_init<<<N_TOK / TPB, TPB, 0, stream>>>(x, pW, pb, itmp, states, tempers, done, meta);
  for (int h = 0; h < NHOPS; ++h) {
    int* cnt_h = meta + h * TN;
    int* cnt_n = meta + (h + 1) * TN;
    int* cur_h = meta + 60 + h * TN;
    int* off_h = meta + 108 + h * (TN + 1);
    k_prefix<<<1, 64, 0, stream>>>(cnt_h, off_h);
    k_scatter<<<N_TOK / TPB, TPB, 0, stream>>>(tempers, done, off_h, cur_h, compact);
    k_hop<<<N_TOK / TOKB + TN, TPB_HOP, 0, stream>>>(states, tempers, done, compact, cnt_h, off_h,
        w1f, b1, w2f, b2, rw1f, rb1, rw2f, rb2, cnt_n, hcs[h]);
  }
  float* pred = (float*)d_out;
  float* errp = pred + (size_t)N_TOK * DIN;
  k_pred<<<N_TOK / 4, TPB, 0, stream>>>(states, x, pdW, pdb, pred, errp);
}

// Round 9
// 260.565 us; speedup vs baseline: 2.2276x; 1.2771x over previous
//
#include <hip/hip_runtime.h>
#include <cstring>
#include <cmath>
#include <cstdint>

#define N_TOK 65536
#define DIN 128
#define HD 64
#define TN 12
#define ON 3
#define NHOPS 4
#define TPB 256
#define TPB_HOP 512      // 8 waves; wave owns a 32x16 D-tile (2 m-tiles x 1 n-tile)
#define TOKB 64          // tokens per k_hop block (48KB LDS -> 3 blocks/CU)
#define NCAT 13

typedef __attribute__((ext_vector_type(8))) short short8v;     // 8 bf16 frag
typedef __attribute__((ext_vector_type(4))) float f32x4;
typedef __attribute__((ext_vector_type(4))) unsigned short ushort4v;
typedef __attribute__((ext_vector_type(8))) unsigned short ushort8v;

struct HopConst {
  float w[TN][ON];
  unsigned ck0, ck1;
  int last_hop;
};

// ---- threefry2x32 (exact JAX semantics) ----
__host__ __device__ __forceinline__ void tf2x32(unsigned k0, unsigned k1,
                                                unsigned x0, unsigned x1,
                                                unsigned& o0, unsigned& o1) {
  unsigned ks2 = k0 ^ k1 ^ 0x1BD11BDAu;
  x0 += k0; x1 += k1;
#define TFR(r) { x0 += x1; x1 = (x1 << (r)) | (x1 >> (32 - (r))); x1 ^= x0; }
  TFR(13) TFR(15) TFR(26) TFR(6)
  x0 += k1;  x1 += ks2 + 1u;
  TFR(17) TFR(29) TFR(16) TFR(24)
  x0 += ks2; x1 += k0 + 2u;
  TFR(13) TFR(15) TFR(26) TFR(6)
  x0 += k0;  x1 += k1 + 3u;
  TFR(17) TFR(29) TFR(16) TFR(24)
  x0 += k1;  x1 += ks2 + 4u;
  TFR(13) TFR(15) TFR(26) TFR(6)
  x0 += ks2; x1 += k0 + 5u;
#undef TFR
  o0 = x0; o1 = x1;
}
__host__ __device__ __forceinline__ unsigned tf_bits32(unsigned k0, unsigned k1, unsigned j) {
  unsigned o0, o1;
  tf2x32(k0, k1, 0u, j, o0, o1);
  return o0 ^ o1;
}

// ---- bf16x3 splitting ----
__host__ __device__ __forceinline__ unsigned short bf16r(float v) {
  unsigned u = __builtin_bit_cast(unsigned, v);
  return (unsigned short)((u + 0x7fffu + ((u >> 16) & 1u)) >> 16);
}
__host__ __device__ __forceinline__ float bf2f(unsigned short s) {
  return __builtin_bit_cast(float, ((unsigned)s) << 16);
}
__host__ __device__ __forceinline__ void split3(float v, unsigned short& a,
                                                unsigned short& b, unsigned short& c) {
  a = bf16r(v); float r = v - bf2f(a);
  b = bf16r(r); r -= bf2f(b);
  c = bf16r(r);
}

// ---- kernels ----

// init: states = x @ proj_W + proj_b via bf16x3 MFMA; tempers/done/histogram
__global__ __launch_bounds__(512, 4) void k_init(
    const float* __restrict__ x, const unsigned short* __restrict__ pjf,
    const float* __restrict__ pb, const int* __restrict__ itemp,
    float* __restrict__ states, int* __restrict__ tempers,
    int* __restrict__ done, int* __restrict__ cnt0)
{
  __shared__ unsigned short sX[3 * 64 * 128];  // 48KB x splits
  __shared__ float sOut[64 * 64];              // 16KB out
  __shared__ int lcnt[TN];
  const int tid = threadIdx.x;
  const int lane = tid & 63;
  const int w = __builtin_amdgcn_readfirstlane(tid >> 6);
  const int mgrp = w & 1, ngrp = w >> 1;       // 2 feat-halves x 4 tok-quarters
  const int bstart = blockIdx.x * 64;

  // stage x (coalesced): thread = (tok=tid>>3, c0=tid&7), 16 k each
  {
    const int tok = tid >> 3, c0 = tid & 7;
    const float* xr = x + (size_t)(bstart + tok) * DIN + c0 * 16;
    float v[16];
    #pragma unroll
    for (int q = 0; q < 4; ++q) {
      const float4 f = *(const float4*)(xr + q * 4);
      v[q*4] = f.x; v[q*4+1] = f.y; v[q*4+2] = f.z; v[q*4+3] = f.w;
    }
    unsigned short sp[3][16];
    #pragma unroll
    for (int i = 0; i < 16; ++i) split3(v[i], sp[0][i], sp[1][i], sp[2][i]);
    #pragma unroll
    for (int s = 0; s < 3; ++s)
      #pragma unroll
      for (int jj = 0; jj < 2; ++jj) {
        ushort8v u;
        #pragma unroll
        for (int i = 0; i < 8; ++i) u[i] = sp[s][jj * 8 + i];
        const int chunk = (2 * c0 + jj) ^ (tok & 7);
        *(ushort8v*)(sX + s * 8192 + tok * 128 + chunk * 8) = u;
      }
  }
  if (tid < TN) lcnt[tid] = 0;
  __syncthreads();

  const f32x4 zf = {0.0f, 0.0f, 0.0f, 0.0f};
  const int tok16 = (lane & 15) + 16 * ngrp;
  short8v bf[3][4];
  #pragma unroll
  for (int s = 0; s < 3; ++s)
    #pragma unroll
    for (int kc = 0; kc < 4; ++kc) {
      const int chunk = (4 * kc + (lane >> 4)) ^ (tok16 & 7);
      bf[s][kc] = *(const short8v*)(sX + s * 8192 + tok16 * 128 + chunk * 8);
    }
  f32x4 acc[2] = {zf, zf};
  #pragma unroll
  for (int sw = 0; sw < 3; ++sw) {
    short8v a[2][4];
    #pragma unroll
    for (int mt = 0; mt < 2; ++mt)
      #pragma unroll
      for (int kc = 0; kc < 4; ++kc)
        a[mt][kc] = *(const short8v*)(pjf +
            (size_t)((sw * 4 + (2 * mgrp + mt)) * 4 + kc) * 512 + lane * 8);
    #pragma unroll
    for (int sa = 0; sa < 3; ++sa) {
      if (sw + sa > 2) continue;
      #pragma unroll
      for (int mt = 0; mt < 2; ++mt)
        #pragma unroll
        for (int kc = 0; kc < 4; ++kc)
          acc[mt] = __builtin_amdgcn_mfma_f32_16x16x32_bf16(
              a[mt][kc], bf[sa][kc], acc[mt], 0, 0, 0);
    }
  }

  // D + bias -> swizzled f32 LDS
  #pragma unroll
  for (int mt = 0; mt < 2; ++mt) {
    const int mt2 = 2 * mgrp + mt;
    const int j0 = 16 * mt2 + 4 * (lane >> 4);
    const float4 bv = *(const float4*)(pb + j0);
    const float bb[4] = {bv.x, bv.y, bv.z, bv.w};
    f32x4 vv;
    #pragma unroll
    for (int r = 0; r < 4; ++r) vv[r] = acc[mt][r] + bb[r];
    const int chunk = (4 * mt2 + (lane >> 4)) ^ (tok16 & 15);
    *(f32x4*)(sOut + tok16 * 64 + chunk * 4) = vv;
  }
  __syncthreads();

  // coalesced states write-back
  {
    const int tok = tid >> 3, c0 = tid & 7;
    const int n = bstart + tok;
    float* wr = states + (size_t)n * HD;
    #pragma unroll
    for (int q = 0; q < 2; ++q) {
      const int c = c0 + 8 * q;
      const int cs = c ^ (tok & 15);
      *(float4*)(wr + c * 4) = *(const float4*)(sOut + tok * 64 + cs * 4);
    }
  }
  if (tid < 64) {
    const int n = bstart + tid;
    const int t = itemp[n];
    tempers[n] = t;
    done[n] = 0;
    atomicAdd(&lcnt[t], 1);
  }
  __syncthreads();
  if (tid < TN && lcnt[tid] > 0) atomicAdd(&cnt0[tid], lcnt[tid]);
}

// one-time: split weights to bf16x3 in MFMA A-frag order.
// A-frag: frag(s, mtile, kc, lane) holds A[m=16*mtile+(lane&15)][k=32*kc+8*(lane>>4)+i]
__global__ __launch_bounds__(TPB) void k_wprep(
    const float* __restrict__ W1, const float* __restrict__ W2,
    const float* __restrict__ rW1, const float* __restrict__ rW2,
    const float* __restrict__ pjW, const float* __restrict__ pdW,
    unsigned short* __restrict__ w1f, unsigned short* __restrict__ w2f,
    unsigned short* __restrict__ rw1f, unsigned short* __restrict__ rw2f,
    unsigned short* __restrict__ pjf, unsigned short* __restrict__ pwf)
{
  const int idx = blockIdx.x * TPB + threadIdx.x;
  const int NU1 = TN * ON * 4 * 2 * 64;   // 18432
  const int NU2 = 4 * 2 * 64;             // 512
  const int NU3 = 2 * 64;                 // 128
  const int NU4 = 4 * 4 * 64;             // 1024 proj_W (4 mt x 4 kc)
  const int NU5 = 8 * 2 * 64;             // 1024 pred_W (8 mt x 2 kc)
  if (idx < NU1) {
    const int lane = idx & 63, kc = (idx >> 6) & 1, mt = (idx >> 7) & 3, mat = idx >> 9;
    const int j = 16 * mt + (lane & 15);
    const int h0 = 32 * kc + 8 * (lane >> 4);
    const float* s1 = W1 + (size_t)mat * 4096;
    const float* s2 = W2 + (size_t)mat * 4096;
    #pragma unroll
    for (int i = 0; i < 8; ++i) {
      unsigned short a0, a1, a2;
      const size_t base = (size_t)mat * 12288 + (size_t)(mt * 2 + kc) * 512 + lane * 8 + i;
      split3(s1[(h0 + i) * 64 + j], a0, a1, a2);
      w1f[base] = a0; w1f[base + 4096] = a1; w1f[base + 8192] = a2;
      split3(s2[(h0 + i) * 64 + j], a0, a1, a2);
      w2f[base] = a0; w2f[base + 4096] = a1; w2f[base + 8192] = a2;
    }
  } else if (idx < NU1 + NU2) {
    const int u = idx - NU1;
    const int lane = u & 63, kc = (u >> 6) & 1, mt = (u >> 7) & 3;
    const int j = 16 * mt + (lane & 15);
    const int h0 = 32 * kc + 8 * (lane >> 4);
    #pragma unroll
    for (int i = 0; i < 8; ++i) {
      unsigned short a0, a1, a2;
      const size_t base = (size_t)(mt * 2 + kc) * 512 + lane * 8 + i;
      split3(rW1[(h0 + i) * 64 + j], a0, a1, a2);
      rw1f[base] = a0; rw1f[base + 4096] = a1; rw1f[base + 8192] = a2;
    }
  } else if (idx < NU1 + NU2 + NU3) {
    const int u = idx - NU1 - NU2;
    const int lane = u & 63, kc = (u >> 6) & 1;
    const int c = lane & 15;
    const int h0 = 32 * kc + 8 * (lane >> 4);
    #pragma unroll
    for (int i = 0; i < 8; ++i) {
      unsigned short a0, a1, a2;
      const float v = (c < NCAT) ? rW2[(h0 + i) * NCAT + c] : 0.0f;
      split3(v, a0, a1, a2);
      const size_t base = (size_t)kc * 512 + lane * 8 + i;
      rw2f[base] = a0; rw2f[base + 1024] = a1; rw2f[base + 2048] = a2;
    }
  } else if (idx < NU1 + NU2 + NU3 + NU4) {
    const int u = idx - (NU1 + NU2 + NU3);
    const int lane = u & 63, kc = (u >> 6) & 3, mt = u >> 8;
    const int j = 16 * mt + (lane & 15);
    const int k0 = 32 * kc + 8 * (lane >> 4);
    #pragma unroll
    for (int i = 0; i < 8; ++i) {
      unsigned short a0, a1, a2;
      split3(pjW[(size_t)(k0 + i) * 64 + j], a0, a1, a2);
      const size_t base = (size_t)(mt * 4 + kc) * 512 + lane * 8 + i;
      pjf[base] = a0; pjf[base + 8192] = a1; pjf[base + 16384] = a2;
    }
  } else if (idx < NU1 + NU2 + NU3 + NU4 + NU5) {
    const int u = idx - (NU1 + NU2 + NU3 + NU4);
    const int lane = u & 63, kc = (u >> 6) & 1, mt = u >> 7;
    const int d = 16 * mt + (lane & 15);
    const int h0 = 32 * kc + 8 * (lane >> 4);
    #pragma unroll
    for (int i = 0; i < 8; ++i) {
      unsigned short a0, a1, a2;
      split3(pdW[(size_t)(h0 + i) * 128 + d], a0, a1, a2);
      const size_t base = (size_t)(mt * 2 + kc) * 512 + lane * 8 + i;
      pwf[base] = a0; pwf[base + 8192] = a1; pwf[base + 16384] = a2;
    }
  }
}

__global__ void k_prefix(const int* __restrict__ cnt, int* __restrict__ offp) {
  if (threadIdx.x == 0 && blockIdx.x == 0) {
    int o = 0;
    for (int t = 0; t < TN; ++t) { offp[t] = o; o += (cnt[t] + TOKB - 1) & ~(TOKB - 1); }
    offp[TN] = o;
  }
}

__global__ __launch_bounds__(TPB) void k_scatter(
    const int* __restrict__ tempers, const int* __restrict__ done,
    const int* __restrict__ offp, int* __restrict__ cursor, int* __restrict__ compact)
{
  __shared__ int lcnt[TN], lbase[TN];
  const int tid = threadIdx.x;
  if (tid < TN) lcnt[tid] = 0;
  __syncthreads();
  const int n = blockIdx.x * TPB + tid;
  int t = -1, lpos = 0;
  if (!done[n]) { t = tempers[n]; lpos = atomicAdd(&lcnt[t], 1); }
  __syncthreads();
  if (tid < TN && lcnt[tid] > 0) lbase[tid] = atomicAdd(&cursor[tid], lcnt[tid]);
  __syncthreads();
  if (t >= 0) compact[offp[t] + lbase[t] + lpos] = n;
}

// B-frag fetch from swizzled LDS acts ([s][tok][h] bf16, 16B chunks XOR tok&7)
__device__ __forceinline__ short8v bfrag(const unsigned short* sBase, int s, int ntile,
                                         int kc, int lane) {
  const int tok = (lane & 15) + 16 * ntile;
  const int chunk = (4 * kc + (lane >> 4)) ^ (tok & 7);
  return *(const short8v*)(sBase + s * 4096 + tok * 64 + chunk * 8);
}

__device__ __forceinline__ void load_bfrags(const unsigned short* sBase, int ngrp, int lane,
                                            short8v bf[3][2]) {
  #pragma unroll
  for (int s = 0; s < 3; ++s)
    #pragma unroll
    for (int kc = 0; kc < 2; ++kc)
      bf[s][kc] = bfrag(sBase, s, ngrp, kc, lane);
}

// 6-pass bf16x3 MFMA accumulate into 2 D-tiles (mt), single n-tile
__device__ __forceinline__ void mfma_all(const unsigned short* __restrict__ Ag,
                                         const short8v bf[3][2],
                                         int mgrp, int lane, f32x4 acc[2]) {
  #pragma unroll
  for (int sw = 0; sw < 3; ++sw) {
    short8v a[2][2];
    #pragma unroll
    for (int mt = 0; mt < 2; ++mt)
      #pragma unroll
      for (int kc = 0; kc < 2; ++kc)
        a[mt][kc] = *(const short8v*)(Ag +
            (size_t)((sw * 4 + (2 * mgrp + mt)) * 2 + kc) * 512 + lane * 8);
    #pragma unroll
    for (int sa = 0; sa < 3; ++sa) {
      if (sw + sa > 2) continue;
      #pragma unroll
      for (int mt = 0; mt < 2; ++mt)
        #pragma unroll
        for (int kc = 0; kc < 2; ++kc)
          acc[mt] = __builtin_amdgcn_mfma_f32_16x16x32_bf16(
              a[mt][kc], bf[sa][kc], acc[mt], 0, 0, 0);
    }
  }
}

// bias + relu + split3 -> swizzled LDS store ([s][tok][h] bf16)
__device__ __forceinline__ void store_h1(const f32x4 acc[2], const float* __restrict__ bias,
                                         unsigned short* dst, int mgrp, int ngrp, int lane) {
  const int tok = (lane & 15) + 16 * ngrp;
  #pragma unroll
  for (int mt = 0; mt < 2; ++mt) {
    const int mt2 = 2 * mgrp + mt;
    const int j0 = 16 * mt2 + 4 * (lane >> 4);
    const float4 bv = *(const float4*)(bias + j0);
    const float bb[4] = {bv.x, bv.y, bv.z, bv.w};
    ushort4v u0, u1, u2;
    #pragma unroll
    for (int r = 0; r < 4; ++r) {
      const float v = fmaxf(acc[mt][r] + bb[r], 0.0f);
      unsigned short a, b, c;
      split3(v, a, b, c);
      u0[r] = a; u1[r] = b; u2[r] = c;
    }
    const int chunk = (2 * mt2 + ((lane >> 4) >> 1)) ^ (tok & 7);
    const int half = (lane >> 4) & 1;
    const int base = tok * 64 + chunk * 8 + half * 4;
    *(ushort4v*)(dst + base) = u0;
    *(ushort4v*)(dst + 4096 + base) = u1;
    *(ushort4v*)(dst + 8192 + base) = u2;
  }
}

// main per-hop kernel: bf16x3 MFMA, weights frag-ordered global (L2-hot),
// acts via swizzled LDS. 48KB LDS -> 3 blocks/CU co-resident.
__global__ __launch_bounds__(TPB_HOP, 6) void k_hop(
    float* __restrict__ states, int* __restrict__ tempers, int* __restrict__ done,
    const int* __restrict__ compact, const int* __restrict__ cnt,
    const int* __restrict__ offp,
    const unsigned short* __restrict__ w1f, const float* __restrict__ b1,
    const unsigned short* __restrict__ w2f, const float* __restrict__ b2,
    const unsigned short* __restrict__ rw1f, const float* __restrict__ rb1,
    const unsigned short* __restrict__ rw2f, const float* __restrict__ rb2,
    int* __restrict__ cnt_next, HopConst hc)
{
  __shared__ unsigned short sX[3 * TOKB * HD];   // 24KB acts splits / logits f32
  __shared__ unsigned short sH[3 * TOKB * HD];   // 24KB h1 splits / out f32
  __shared__ int stok[TOKB];
  __shared__ unsigned char sact[TOKB];
  __shared__ int lcnt[TN];

  const int tid = threadIdx.x;
  const int lane = tid & 63;
  const int w = __builtin_amdgcn_readfirstlane(tid >> 6);
  const int mgrp = w & 1, ngrp = w >> 1;          // 2 feat-halves x 4 tok-quarters
  const int bstart = blockIdx.x * TOKB;
  if (bstart >= offp[TN]) return;
  int tt = 0;
  #pragma unroll
  for (int i = 1; i < TN; ++i) if (bstart >= offp[i]) tt = i;
  const int t = __builtin_amdgcn_readfirstlane(tt);
  const int cntt = cnt[t];
  const int slot = tid & 63;
  const int hq = tid >> 6;                        // 8 h-values per thread

  // ---- stage states: f32 -> bf16x3 swizzled LDS ----
  {
    const int pos = bstart + slot;
    const bool a = (pos - offp[t]) < cntt;
    const int tok = compact[a ? pos : offp[t]];
    if (hq == 0) { stok[slot] = tok; sact[slot] = a ? 1 : 0; }
    const float* sr = states + (size_t)tok * HD + hq * 8;
    float v[8];
    #pragma unroll
    for (int q = 0; q < 2; ++q) {
      const float4 f = *(const float4*)(sr + q * 4);
      v[q*4] = f.x; v[q*4+1] = f.y; v[q*4+2] = f.z; v[q*4+3] = f.w;
    }
    unsigned short sp[3][8];
    #pragma unroll
    for (int i = 0; i < 8; ++i) split3(v[i], sp[0][i], sp[1][i], sp[2][i]);
    const int chunk = hq ^ (slot & 7);
    #pragma unroll
    for (int s = 0; s < 3; ++s) {
      ushort8v u;
      #pragma unroll
      for (int i = 0; i < 8; ++i) u[i] = sp[s][i];
      *(ushort8v*)(sX + s * 4096 + slot * 64 + chunk * 8) = u;
    }
  }
  if (tid < TN) lcnt[tid] = 0;
  __syncthreads();

  const f32x4 zf = {0.0f, 0.0f, 0.0f, 0.0f};
  f32x4 out[2] = {zf, zf};

  #pragma unroll 1
  for (int o = 0; o < ON; ++o) {
    const int mat = t * ON + o;
    // L1
    short8v bf[3][2];
    load_bfrags(sX, ngrp, lane, bf);
    f32x4 acc[2] = {zf, zf};
    mfma_all(w1f + (size_t)mat * 12288, bf, mgrp, lane, acc);
    __syncthreads();                         // prev L2 readers of sH done
    store_h1(acc, b1 + mat * 64, sH, mgrp, ngrp, lane);
    __syncthreads();                         // h1 splits visible
    // L2
    load_bfrags(sH, ngrp, lane, bf);
    f32x4 acc2[2] = {zf, zf};
    mfma_all(w2f + (size_t)mat * 12288, bf, mgrp, lane, acc2);
    const float wo = hc.w[t][o];
    #pragma unroll
    for (int mt = 0; mt < 2; ++mt) {
      const int j0 = 16 * (2 * mgrp + mt) + 4 * (lane >> 4);
      const float4 bv = *(const float4*)(b2 + mat * 64 + j0);
      const float bb[4] = {bv.x, bv.y, bv.z, bv.w};
      #pragma unroll
      for (int r = 0; r < 4; ++r)
        out[mt][r] = fmaf(wo, fmaxf(acc2[mt][r] + bb[r], 0.0f), out[mt][r]);
    }
  }
  __syncthreads();                           // all sH/sX reads done

  // ---- out: f32 -> sH (swizzled f32) ; splits -> sX for routing ----
  float* sHf = (float*)sH;
  {
    const int tok = (lane & 15) + 16 * ngrp;
    #pragma unroll
    for (int mt = 0; mt < 2; ++mt) {
      const int mt2 = 2 * mgrp + mt;
      const int chunk = (4 * mt2 + (lane >> 4)) ^ (tok & 15);
      *(f32x4*)(sHf + tok * 64 + chunk * 4) = out[mt];
    }
    if (!hc.last_hop) {
      #pragma unroll
      for (int mt = 0; mt < 2; ++mt) {
        const int mt2 = 2 * mgrp + mt;
        ushort4v u0, u1, u2;
        #pragma unroll
        for (int r = 0; r < 4; ++r) {
          unsigned short a, b, c;
          split3(out[mt][r], a, b, c);
          u0[r] = a; u1[r] = b; u2[r] = c;
        }
        const int chunk = (2 * mt2 + ((lane >> 4) >> 1)) ^ (tok & 7);
        const int half = (lane >> 4) & 1;
        const int base = tok * 64 + chunk * 8 + half * 4;
        *(ushort4v*)(sX + base) = u0;
        *(ushort4v*)(sX + 4096 + base) = u1;
        *(ushort4v*)(sX + 8192 + base) = u2;
      }
    }
  }
  __syncthreads();                           // out f32 + splits visible

  // ---- coalesced states write-back from sHf ----
  if (sact[slot]) {
    float* wr = states + (size_t)stok[slot] * HD + hq * 8;
    #pragma unroll
    for (int cc = 0; cc < 2; ++cc) {
      const int chunk = (2 * hq + cc) ^ (slot & 15);
      *(float4*)(wr + cc * 4) = *(const float4*)(sHf + slot * 64 + chunk * 4);
    }
  }
  if (hc.last_hop) return;

  // ---- r1 = relu(out @ rW1 + rb1) ----
  {
    short8v bf[3][2];
    load_bfrags(sX, ngrp, lane, bf);
    f32x4 acc[2] = {zf, zf};
    mfma_all(rw1f, bf, mgrp, lane, acc);
    __syncthreads();                         // write-back reads of sHf done
    store_h1(acc, rb1, sH, mgrp, ngrp, lane);
  }
  __syncthreads();                           // r1 splits visible

  // ---- logits = r1 @ rW2 (waves 0..3 own n-tiles); bias added in sampler ----
  if (w < 4) {
    short8v bfr[3][2];
    #pragma unroll
    for (int s = 0; s < 3; ++s)
      #pragma unroll
      for (int kc = 0; kc < 2; ++kc)
        bfr[s][kc] = bfrag(sH, s, w, kc, lane);
    f32x4 acc = zf;
    #pragma unroll
    for (int sw = 0; sw < 3; ++sw) {
      short8v a[2];
      #pragma unroll
      for (int kc = 0; kc < 2; ++kc)
        a[kc] = *(const short8v*)(rw2f + (size_t)(sw * 2 + kc) * 512 + lane * 8);
      #pragma unroll
      for (int sa = 0; sa < 3; ++sa) {
        if (sw + sa > 2) continue;
        #pragma unroll
        for (int kc = 0; kc < 2; ++kc)
          acc = __builtin_amdgcn_mfma_f32_16x16x32_bf16(a[kc], bfr[sa][kc], acc, 0, 0, 0);
      }
    }
    float* sXf = (float*)sX;
    const int tok = (lane & 15) + 16 * w;
    *(f32x4*)(sXf + tok * 16 + (lane >> 4) * 4) = acc;
  }
  __syncthreads();

  // ---- gumbel-argmax sample, one thread per token ----
  if (tid < TOKB && sact[tid]) {
    const float* lrow = (const float*)sX + tid * 16;
    const int token = stok[tid];
    const unsigned jbase = (unsigned)token * (unsigned)NCAT;
    float best = -3.0e38f; int bc = 0;
    #pragma unroll
    for (int c = 0; c < NCAT; ++c) {
      const float L = lrow[c] + rb2[c];
      const unsigned bits = tf_bits32(hc.ck0, hc.ck1, jbase + (unsigned)c);
      const float u = __uint_as_float((bits >> 9) | 0x3f800000u) - 1.0f;
      float val = u + 1.17549435e-38f;
      val = fmaxf(val, 1.17549435e-38f);
      const float g = -logf(-logf(val));
      const float sc = L + g;
      if (sc > best) { best = sc; bc = c; }   // strict > keeps first max
    }
    const int nt = bc < (TN - 1) ? bc : (TN - 1);
    tempers[token] = nt;
    if (bc == TN) done[token] = 1;
    else atomicAdd(&lcnt[nt], 1);
  }
  __syncthreads();
  if (tid < TN && lcnt[tid] > 0) atomicAdd(&cnt_next[tid], lcnt[tid]);
}

// pred = states @ pred_W + pred_b via bf16x3 MFMA; fused err reduction
__global__ __launch_bounds__(512, 4) void k_pred(
    const float* __restrict__ states, const float* __restrict__ x,
    const unsigned short* __restrict__ pwf, const float* __restrict__ pdb,
    float* __restrict__ pred, float* __restrict__ err)
{
  __shared__ unsigned short sX[3 * 64 * 64];   // 24KB states splits
  __shared__ float sP[64 * 128];               // 32KB pred
  const int tid = threadIdx.x;
  const int lane = tid & 63;
  const int w = __builtin_amdgcn_readfirstlane(tid >> 6);
  const int mgrp = w & 3, ngrp = w >> 2;       // 4 d-quarters x 2 tok-halves
  const int bstart = blockIdx.x * 64;

  // stage states (coalesced): thread = (tok=tid>>3, c0=tid&7), 8 h each
  {
    const int tok = tid >> 3, c0 = tid & 7;
    const float* sr = states + (size_t)(bstart + tok) * HD + c0 * 8;
    float v[8];
    #pragma unroll
    for (int q = 0; q < 2; ++q) {
      const float4 f = *(const float4*)(sr + q * 4);
      v[q*4] = f.x; v[q*4+1] = f.y; v[q*4+2] = f.z; v[q*4+3] = f.w;
    }
    unsigned short sp[3][8];
    #pragma unroll
    for (int i = 0; i < 8; ++i) split3(v[i], sp[0][i], sp[1][i], sp[2][i]);
    const int chunk = c0 ^ (tok & 7);
    #pragma unroll
    for (int s = 0; s < 3; ++s) {
      ushort8v u;
      #pragma unroll
      for (int i = 0; i < 8; ++i) u[i] = sp[s][i];
      *(ushort8v*)(sX + s * 4096 + tok * 64 + chunk * 8) = u;
    }
  }
  __syncthreads();

  const f32x4 zf = {0.0f, 0.0f, 0.0f, 0.0f};
  short8v bf[3][2][2];
  #pragma unroll
  for (int s = 0; s < 3; ++s)
    #pragma unroll
    for (int nt = 0; nt < 2; ++nt)
      #pragma unroll
      for (int kc = 0; kc < 2; ++kc)
        bf[s][nt][kc] = bfrag(sX, s, 2 * ngrp + nt, kc, lane);

  f32x4 acc[2][2] = {{zf, zf}, {zf, zf}};
  #pragma unroll
  for (int sw = 0; sw < 3; ++sw) {
    short8v a[2][2];
    #pragma unroll
    for (int mt = 0; mt < 2; ++mt)
      #pragma unroll
      for (int kc = 0; kc < 2; ++kc)
        a[mt][kc] = *(const short8v*)(pwf +
            (size_t)((sw * 8 + (2 * mgrp + mt)) * 2 + kc) * 512 + lane * 8);
    #pragma unroll
    for (int sa = 0; sa < 3; ++sa) {
      if (sw + sa > 2) continue;
      #pragma unroll
      for (int mt = 0; mt < 2; ++mt)
        #pragma unroll
        for (int nt = 0; nt < 2; ++nt)
          #pragma unroll
          for (int kc = 0; kc < 2; ++kc)
            acc[mt][nt] = __builtin_amdgcn_mfma_f32_16x16x32_bf16(
                a[mt][kc], bf[sa][nt][kc], acc[mt][nt], 0, 0, 0);
    }
  }

  // D + bias -> swizzled f32 LDS
  #pragma unroll
  for (int mt = 0; mt < 2; ++mt) {
    const int mt2 = 2 * mgrp + mt;
    const int d0 = 16 * mt2 + 4 * (lane >> 4);
    const float4 bv = *(const float4*)(pdb + d0);
    const float bb[4] = {bv.x, bv.y, bv.z, bv.w};
    #pragma unroll
    for (int nt = 0; nt < 2; ++nt) {
      const int tok = (lane & 15) + 16 * (2 * ngrp + nt);
      f32x4 vv;
      #pragma unroll
      for (int r = 0; r < 4; ++r) vv[r] = acc[mt][nt][r] + bb[r];
      const int chunk = (d0 >> 2) ^ (tok & 7);
      *(f32x4*)(sP + tok * 128 + chunk * 4) = vv;
    }
  }
  __syncthreads();

  // coalesced pred write + fused err
  {
    const int tok = tid >> 3, c0 = tid & 7;
    const int n = bstart + tok;
    const float* xr = x + (size_t)n * DIN;
    float* pr = pred + (size_t)n * DIN;
    float s = 0.0f;
    #pragma unroll
    for (int q = 0; q < 4; ++q) {
      const int c = c0 + 8 * q;
      const int cs = c ^ (tok & 7);
      const f32x4 pv = *(const f32x4*)(sP + tok * 128 + cs * 4);
      const float4 xv = *(const float4*)(xr + c * 4);
      float4 ov; ov.x = pv[0]; ov.y = pv[1]; ov.z = pv[2]; ov.w = pv[3];
      *(float4*)(pr + c * 4) = ov;
      const float e0 = pv[0] - xv.x, e1 = pv[1] - xv.y, e2 = pv[2] - xv.z, e3 = pv[3] - xv.w;
      s += e0 * e0 + e1 * e1 + e2 * e2 + e3 * e3;
    }
    s += __shfl_xor(s, 1, 64);
    s += __shfl_xor(s, 2, 64);
    s += __shfl_xor(s, 4, 64);
    if (c0 == 0) err[n] = s * (1.0f / 128.0f);
  }
}

// ---- host-side RNG constant derivation ----
static float host_erfinv(float xf) {
  double x = xf;
  double w = -log1p(-x * x);
  double p;
  if (w < 5.0) {
    w -= 2.5;
    p = 2.81022636e-08;          p = 3.43273939e-07 + p * w;
    p = -3.5233877e-06 + p * w;  p = -4.39150654e-06 + p * w;
    p = 0.00021858087 + p * w;   p = -0.00125372503 + p * w;
    p = -0.00417768164 + p * w;  p = 0.246640727 + p * w;
    p = 1.50140941 + p * w;
  } else {
    w = sqrt(w) - 3.0;
    p = -0.000200214257;         p = 0.000100950558 + p * w;
    p = 0.00134934322 + p * w;   p = -0.00367342844 + p * w;
    p = 0.00573950773 + p * w;   p = -0.0076224613 + p * w;
    p = 0.00943887047 + p * w;   p = 1.00167406 + p * w;
    p = 2.83297682 + p * w;
  }
  return (float)(p * x);
}

static void build_hops(HopConst* hcs) {
  const float lo = nextafterf(-1.0f, 0.0f);
  const unsigned rk0 = 0u, rk1 = 42u;
  for (int hop = 0; hop < NHOPS; ++hop) {
    unsigned hk0, hk1;
    tf2x32(rk0, rk1, 0u, (unsigned)hop, hk0, hk1);
    for (int t = 0; t < TN; ++t) {
      unsigned tk0, tk1;
      tf2x32(hk0, hk1, 0u, (unsigned)t, tk0, tk1);
      double nrm[3];
      for (int i = 0; i < 3; ++i) {
        const unsigned bits = tf_bits32(tk0, tk1, (unsigned)i);
        unsigned ub = (bits >> 9) | 0x3f800000u;
        float f; memcpy(&f, &ub, 4);
        const float u01 = f - 1.0f;
        float val = u01 * 2.0f + lo;
        if (val < lo) val = lo;
        const float ef = host_erfinv(val);
        nrm[i] = (double)(1.41421356f * ef);
      }
      const double m = fmax(nrm[0], fmax(nrm[1], nrm[2]));
      const double e0 = exp(nrm[0] - m), e1 = exp(nrm[1] - m), e2 = exp(nrm[2] - m);
      const double s = e0 + e1 + e2;
      hcs[hop].w[t][0] = (float)(e0 / s);
      hcs[hop].w[t][1] = (float)(e1 / s);
      hcs[hop].w[t][2] = (float)(e2 / s);
    }
    unsigned ck0, ck1;
    tf2x32(hk0, hk1, 0u, 10000u, ck0, ck1);
    hcs[hop].ck0 = ck0; hcs[hop].ck1 = ck1;
    hcs[hop].last_hop = (hop == NHOPS - 1) ? 1 : 0;
  }
}

extern "C" void kernel_launch(void* const* d_in, const int* in_sizes, int n_in,
                              void* d_out, int out_size, void* d_ws, size_t ws_size,
                              hipStream_t stream) {
  (void)in_sizes; (void)n_in; (void)out_size; (void)ws_size;
  const float* x    = (const float*)d_in[0];
  const float* pW   = (const float*)d_in[1];
  const float* pb   = (const float*)d_in[2];
  const float* W1   = (const float*)d_in[3];
  const float* b1   = (const float*)d_in[4];
  const float* W2   = (const float*)d_in[5];
  const float* b2   = (const float*)d_in[6];
  const float* rW1  = (const float*)d_in[7];
  const float* rb1  = (const float*)d_in[8];
  const float* rW2  = (const float*)d_in[9];
  const float* rb2  = (const float*)d_in[10];
  const float* pdW  = (const float*)d_in[11];
  const float* pdb  = (const float*)d_in[12];
  const int*   itmp = (const int*)d_in[13];

  // ws: [meta 1KB][tempers N][done N][compact N+TN*TOKB][states N*64 f32]
  //     [w1f][w2f][rw1f][rw2f][pjf][pwf] (u16 frag arrays)
  int* meta    = (int*)d_ws;
  int* tempers = (int*)((char*)d_ws + 1024);
  int* done    = tempers + N_TOK;
  int* compact = done + N_TOK;
  float* states = (float*)(compact + N_TOK + TN * TOKB);
  unsigned short* w1f  = (unsigned short*)(states + (size_t)N_TOK * HD);
  unsigned short* w2f  = w1f + (size_t)TN * ON * 12288;
  unsigned short* rw1f = w2f + (size_t)TN * ON * 12288;
  unsigned short* rw2f = rw1f + 12288;
  unsigned short* pjf  = rw2f + 3072;
  unsigned short* pwf  = pjf + 24576;

  HopConst hcs[NHOPS];
  build_hops(hcs);

  hipMemsetAsync(meta, 0, 160 * sizeof(int), stream);
  k_wprep<<<83, TPB, 0, stream>>>(W1, W2, rW1, rW2, pW, pdW,
                                  w1f, w2f, rw1f, rw2f, pjf, pwf);
  k_init<<<N_TOK / 64, 512, 0, stream>>>(x, pjf, pb, itmp, states, tempers, done, meta);
  for (int h = 0; h < NHOPS; ++h) {
    int* cnt_h = meta + h * TN;
    int* cnt_n = meta + (h + 1) * TN;
    int* cur_h = meta + 60 + h * TN;
    int* off_h = meta + 108 + h * (TN + 1);
    k_prefix<<<1, 64, 0, stream>>>(cnt_h, off_h);
    k_scatter<<<N_TOK / TPB, TPB, 0, stream>>>(tempers, done, off_h, cur_h, compact);
    k_hop<<<N_TOK / TOKB + TN, TPB_HOP, 0, stream>>>(states, tempers, done, compact, cnt_h, off_h,
        w1f, b1, w2f, b2, rw1f, rb1, rw2f, rb2, cnt_n, hcs[h]);
  }
  float* pred = (float*)d_out;
  float* errp = pred + (size_t)N_TOK * DIN;
  k_pred<<<N_TOK / 64, 512, 0, stream>>>(states, x, pwf, pdb, pred, errp);
}

// Round 10
// 236.798 us; speedup vs baseline: 2.4512x; 1.1004x over previous
//
#include <hip/hip_runtime.h>
#include <cstring>
#include <cmath>
#include <cstdint>

#define N_TOK 65536
#define DIN 128
#define HD 64
#define TN 12
#define ON 3
#define NHOPS 4
#define TPB 256
#define TOKB 64          // tokens per k_hop block (4 waves x 16 tokens)
#define NCAT 13

typedef __attribute__((ext_vector_type(8))) short short8v;     // 8 bf16 frag
typedef __attribute__((ext_vector_type(4))) float f32x4;
typedef __attribute__((ext_vector_type(4))) unsigned short ushort4v;
typedef __attribute__((ext_vector_type(8))) unsigned short ushort8v;

struct HopConst {
  float w[TN][ON];
  unsigned ck0, ck1;
  int last_hop;
};

// ---- threefry2x32 (exact JAX semantics) ----
__host__ __device__ __forceinline__ void tf2x32(unsigned k0, unsigned k1,
                                                unsigned x0, unsigned x1,
                                                unsigned& o0, unsigned& o1) {
  unsigned ks2 = k0 ^ k1 ^ 0x1BD11BDAu;
  x0 += k0; x1 += k1;
#define TFR(r) { x0 += x1; x1 = (x1 << (r)) | (x1 >> (32 - (r))); x1 ^= x0; }
  TFR(13) TFR(15) TFR(26) TFR(6)
  x0 += k1;  x1 += ks2 + 1u;
  TFR(17) TFR(29) TFR(16) TFR(24)
  x0 += ks2; x1 += k0 + 2u;
  TFR(13) TFR(15) TFR(26) TFR(6)
  x0 += k0;  x1 += k1 + 3u;
  TFR(17) TFR(29) TFR(16) TFR(24)
  x0 += k1;  x1 += ks2 + 4u;
  TFR(13) TFR(15) TFR(26) TFR(6)
  x0 += ks2; x1 += k0 + 5u;
#undef TFR
  o0 = x0; o1 = x1;
}
__host__ __device__ __forceinline__ unsigned tf_bits32(unsigned k0, unsigned k1, unsigned j) {
  unsigned o0, o1;
  tf2x32(k0, k1, 0u, j, o0, o1);
  return o0 ^ o1;
}

// ---- bf16x3 splitting ----
__host__ __device__ __forceinline__ unsigned short bf16r(float v) {
  unsigned u = __builtin_bit_cast(unsigned, v);
  return (unsigned short)((u + 0x7fffu + ((u >> 16) & 1u)) >> 16);
}
__host__ __device__ __forceinline__ float bf2f(unsigned short s) {
  return __builtin_bit_cast(float, ((unsigned)s) << 16);
}
__host__ __device__ __forceinline__ void split3(float v, unsigned short& a,
                                                unsigned short& b, unsigned short& c) {
  a = bf16r(v); float r = v - bf2f(a);
  b = bf16r(r); r -= bf2f(b);
  c = bf16r(r);
}

// ---- kernels ----

// init: states = x @ proj_W + proj_b via bf16x3 MFMA; tempers/done/histogram
__global__ __launch_bounds__(512, 4) void k_init(
    const float* __restrict__ x, const unsigned short* __restrict__ pjf,
    const float* __restrict__ pb, const int* __restrict__ itemp,
    float* __restrict__ states, int* __restrict__ tempers,
    int* __restrict__ done, int* __restrict__ cnt0)
{
  __shared__ unsigned short sX[3 * 64 * 128];  // 48KB x splits
  __shared__ float sOut[64 * 64];              // 16KB out
  __shared__ int lcnt[TN];
  const int tid = threadIdx.x;
  const int lane = tid & 63;
  const int w = __builtin_amdgcn_readfirstlane(tid >> 6);
  const int mgrp = w & 1, ngrp = w >> 1;       // 2 feat-halves x 4 tok-quarters
  const int bstart = blockIdx.x * 64;

  // stage x (coalesced): thread = (tok=tid>>3, c0=tid&7), 16 k each
  {
    const int tok = tid >> 3, c0 = tid & 7;
    const float* xr = x + (size_t)(bstart + tok) * DIN + c0 * 16;
    float v[16];
    #pragma unroll
    for (int q = 0; q < 4; ++q) {
      const float4 f = *(const float4*)(xr + q * 4);
      v[q*4] = f.x; v[q*4+1] = f.y; v[q*4+2] = f.z; v[q*4+3] = f.w;
    }
    unsigned short sp[3][16];
    #pragma unroll
    for (int i = 0; i < 16; ++i) split3(v[i], sp[0][i], sp[1][i], sp[2][i]);
    #pragma unroll
    for (int s = 0; s < 3; ++s)
      #pragma unroll
      for (int jj = 0; jj < 2; ++jj) {
        ushort8v u;
        #pragma unroll
        for (int i = 0; i < 8; ++i) u[i] = sp[s][jj * 8 + i];
        const int chunk = (2 * c0 + jj) ^ (tok & 7);
        *(ushort8v*)(sX + s * 8192 + tok * 128 + chunk * 8) = u;
      }
  }
  if (tid < TN) lcnt[tid] = 0;
  __syncthreads();

  const f32x4 zf = {0.0f, 0.0f, 0.0f, 0.0f};
  const int tok16 = (lane & 15) + 16 * ngrp;
  short8v bf[3][4];
  #pragma unroll
  for (int s = 0; s < 3; ++s)
    #pragma unroll
    for (int kc = 0; kc < 4; ++kc) {
      const int chunk = (4 * kc + (lane >> 4)) ^ (tok16 & 7);
      bf[s][kc] = *(const short8v*)(sX + s * 8192 + tok16 * 128 + chunk * 8);
    }
  f32x4 acc[2] = {zf, zf};
  #pragma unroll
  for (int sw = 0; sw < 3; ++sw) {
    short8v a[2][4];
    #pragma unroll
    for (int mt = 0; mt < 2; ++mt)
      #pragma unroll
      for (int kc = 0; kc < 4; ++kc)
        a[mt][kc] = *(const short8v*)(pjf +
            (size_t)((sw * 4 + (2 * mgrp + mt)) * 4 + kc) * 512 + lane * 8);
    #pragma unroll
    for (int sa = 0; sa < 3; ++sa) {
      if (sw + sa > 2) continue;
      #pragma unroll
      for (int mt = 0; mt < 2; ++mt)
        #pragma unroll
        for (int kc = 0; kc < 4; ++kc)
          acc[mt] = __builtin_amdgcn_mfma_f32_16x16x32_bf16(
              a[mt][kc], bf[sa][kc], acc[mt], 0, 0, 0);
    }
  }

  // D + bias -> swizzled f32 LDS
  #pragma unroll
  for (int mt = 0; mt < 2; ++mt) {
    const int mt2 = 2 * mgrp + mt;
    const int j0 = 16 * mt2 + 4 * (lane >> 4);
    const float4 bv = *(const float4*)(pb + j0);
    const float bb[4] = {bv.x, bv.y, bv.z, bv.w};
    f32x4 vv;
    #pragma unroll
    for (int r = 0; r < 4; ++r) vv[r] = acc[mt][r] + bb[r];
    const int chunk = (4 * mt2 + (lane >> 4)) ^ (tok16 & 15);
    *(f32x4*)(sOut + tok16 * 64 + chunk * 4) = vv;
  }
  __syncthreads();

  // coalesced states write-back
  {
    const int tok = tid >> 3, c0 = tid & 7;
    const int n = bstart + tok;
    float* wr = states + (size_t)n * HD;
    #pragma unroll
    for (int q = 0; q < 2; ++q) {
      const int c = c0 + 8 * q;
      const int cs = c ^ (tok & 15);
      *(float4*)(wr + c * 4) = *(const float4*)(sOut + tok * 64 + cs * 4);
    }
  }
  if (tid < 64) {
    const int n = bstart + tid;
    const int t = itemp[n];
    tempers[n] = t;
    done[n] = 0;
    atomicAdd(&lcnt[t], 1);
  }
  __syncthreads();
  if (tid < TN && lcnt[tid] > 0) atomicAdd(&cnt0[tid], lcnt[tid]);
}

// one-time: split weights to bf16x3 in MFMA A-frag order.
// A-frag: frag(s, mtile, kc, lane) holds A[m=16*mtile+(lane&15)][k=32*kc+8*(lane>>4)+i]
__global__ __launch_bounds__(TPB) void k_wprep(
    const float* __restrict__ W1, const float* __restrict__ W2,
    const float* __restrict__ rW1, const float* __restrict__ rW2,
    const float* __restrict__ pjW, const float* __restrict__ pdW,
    unsigned short* __restrict__ w1f, unsigned short* __restrict__ w2f,
    unsigned short* __restrict__ rw1f, unsigned short* __restrict__ rw2f,
    unsigned short* __restrict__ pjf, unsigned short* __restrict__ pwf)
{
  const int idx = blockIdx.x * TPB + threadIdx.x;
  const int NU1 = TN * ON * 4 * 2 * 64;   // 18432
  const int NU2 = 4 * 2 * 64;             // 512
  const int NU3 = 2 * 64;                 // 128
  const int NU4 = 4 * 4 * 64;             // 1024 proj_W (4 mt x 4 kc)
  const int NU5 = 8 * 2 * 64;             // 1024 pred_W (8 mt x 2 kc)
  if (idx < NU1) {
    const int lane = idx & 63, kc = (idx >> 6) & 1, mt = (idx >> 7) & 3, mat = idx >> 9;
    const int j = 16 * mt + (lane & 15);
    const int h0 = 32 * kc + 8 * (lane >> 4);
    const float* s1 = W1 + (size_t)mat * 4096;
    const float* s2 = W2 + (size_t)mat * 4096;
    #pragma unroll
    for (int i = 0; i < 8; ++i) {
      unsigned short a0, a1, a2;
      const size_t base = (size_t)mat * 12288 + (size_t)(mt * 2 + kc) * 512 + lane * 8 + i;
      split3(s1[(h0 + i) * 64 + j], a0, a1, a2);
      w1f[base] = a0; w1f[base + 4096] = a1; w1f[base + 8192] = a2;
      split3(s2[(h0 + i) * 64 + j], a0, a1, a2);
      w2f[base] = a0; w2f[base + 4096] = a1; w2f[base + 8192] = a2;
    }
  } else if (idx < NU1 + NU2) {
    const int u = idx - NU1;
    const int lane = u & 63, kc = (u >> 6) & 1, mt = (u >> 7) & 3;
    const int j = 16 * mt + (lane & 15);
    const int h0 = 32 * kc + 8 * (lane >> 4);
    #pragma unroll
    for (int i = 0; i < 8; ++i) {
      unsigned short a0, a1, a2;
      const size_t base = (size_t)(mt * 2 + kc) * 512 + lane * 8 + i;
      split3(rW1[(h0 + i) * 64 + j], a0, a1, a2);
      rw1f[base] = a0; rw1f[base + 4096] = a1; rw1f[base + 8192] = a2;
    }
  } else if (idx < NU1 + NU2 + NU3) {
    const int u = idx - NU1 - NU2;
    const int lane = u & 63, kc = (u >> 6) & 1;
    const int c = lane & 15;
    const int h0 = 32 * kc + 8 * (lane >> 4);
    #pragma unroll
    for (int i = 0; i < 8; ++i) {
      unsigned short a0, a1, a2;
      const float v = (c < NCAT) ? rW2[(h0 + i) * NCAT + c] : 0.0f;
      split3(v, a0, a1, a2);
      const size_t base = (size_t)kc * 512 + lane * 8 + i;
      rw2f[base] = a0; rw2f[base + 1024] = a1; rw2f[base + 2048] = a2;
    }
  } else if (idx < NU1 + NU2 + NU3 + NU4) {
    const int u = idx - (NU1 + NU2 + NU3);
    const int lane = u & 63, kc = (u >> 6) & 3, mt = u >> 8;
    const int j = 16 * mt + (lane & 15);
    const int k0 = 32 * kc + 8 * (lane >> 4);
    #pragma unroll
    for (int i = 0; i < 8; ++i) {
      unsigned short a0, a1, a2;
      split3(pjW[(size_t)(k0 + i) * 64 + j], a0, a1, a2);
      const size_t base = (size_t)(mt * 4 + kc) * 512 + lane * 8 + i;
      pjf[base] = a0; pjf[base + 8192] = a1; pjf[base + 16384] = a2;
    }
  } else if (idx < NU1 + NU2 + NU3 + NU4 + NU5) {
    const int u = idx - (NU1 + NU2 + NU3 + NU4);
    const int lane = u & 63, kc = (u >> 6) & 1, mt = u >> 7;
    const int d = 16 * mt + (lane & 15);
    const int h0 = 32 * kc + 8 * (lane >> 4);
    #pragma unroll
    for (int i = 0; i < 8; ++i) {
      unsigned short a0, a1, a2;
      split3(pdW[(size_t)(h0 + i) * 128 + d], a0, a1, a2);
      const size_t base = (size_t)(mt * 2 + kc) * 512 + lane * 8 + i;
      pwf[base] = a0; pwf[base + 8192] = a1; pwf[base + 16384] = a2;
    }
  }
}

__global__ void k_prefix(const int* __restrict__ cnt, int* __restrict__ offp) {
  if (threadIdx.x == 0 && blockIdx.x == 0) {
    int o = 0;
    for (int t = 0; t < TN; ++t) { offp[t] = o; o += (cnt[t] + TOKB - 1) & ~(TOKB - 1); }
    offp[TN] = o;
  }
}

__global__ __launch_bounds__(TPB) void k_scatter(
    const int* __restrict__ tempers, const int* __restrict__ done,
    const int* __restrict__ offp, int* __restrict__ cursor, int* __restrict__ compact)
{
  __shared__ int lcnt[TN], lbase[TN];
  const int tid = threadIdx.x;
  if (tid < TN) lcnt[tid] = 0;
  __syncthreads();
  const int n = blockIdx.x * TPB + tid;
  int t = -1, lpos = 0;
  if (!done[n]) { t = tempers[n]; lpos = atomicAdd(&lcnt[t], 1); }
  __syncthreads();
  if (tid < TN && lcnt[tid] > 0) lbase[tid] = atomicAdd(&cursor[tid], lcnt[tid]);
  __syncthreads();
  if (t >= 0) compact[offp[t] + lbase[t] + lpos] = n;
}

// ---- wave-local helpers (16 tokens x 64 features per wave) ----

// scratch layout per split s: idx = n*64 + ((f>>3)^(n&7))*8 + (f&7)  (u16 units)
__device__ __forceinline__ void load_bf(const unsigned short* src, int lane, short8v bf[3][2]) {
  const int n = lane & 15, g = lane >> 4;
  #pragma unroll
  for (int s = 0; s < 3; ++s)
    #pragma unroll
    for (int kc = 0; kc < 2; ++kc) {
      const int chunk = (4 * kc + g) ^ (n & 7);
      bf[s][kc] = *(const short8v*)(src + s * 1024 + n * 64 + chunk * 8);
    }
}

// 6-pass bf16x3 MFMA, 4 m-tiles (full 64 features) x 16 tokens
__device__ __forceinline__ void mfma_all4(const unsigned short* __restrict__ Ag,
                                          const short8v bf[3][2], int lane, f32x4 acc[4]) {
  #pragma unroll
  for (int sw = 0; sw < 3; ++sw) {
    short8v a[4][2];
    #pragma unroll
    for (int mt = 0; mt < 4; ++mt)
      #pragma unroll
      for (int kc = 0; kc < 2; ++kc)
        a[mt][kc] = *(const short8v*)(Ag +
            (size_t)((sw * 4 + mt) * 2 + kc) * 512 + lane * 8);
    #pragma unroll
    for (int sa = 0; sa < 3; ++sa) {
      if (sw + sa > 2) continue;
      #pragma unroll
      for (int mt = 0; mt < 4; ++mt)
        #pragma unroll
        for (int kc = 0; kc < 2; ++kc)
          acc[mt] = __builtin_amdgcn_mfma_f32_16x16x32_bf16(
              a[mt][kc], bf[sa][kc], acc[mt], 0, 0, 0);
    }
  }
}

// bias + relu + split3 -> wave-local swizzled scratch
__device__ __forceinline__ void store4_rb(const f32x4 acc[4], const float* __restrict__ bias,
                                          unsigned short* dst, int lane) {
  const int n = lane & 15, g = lane >> 4;
  #pragma unroll
  for (int mt = 0; mt < 4; ++mt) {
    const int j0 = 16 * mt + 4 * g;
    const float4 bv = *(const float4*)(bias + j0);
    const float bb[4] = {bv.x, bv.y, bv.z, bv.w};
    ushort4v u0, u1, u2;
    #pragma unroll
    for (int r = 0; r < 4; ++r) {
      const float v = fmaxf(acc[mt][r] + bb[r], 0.0f);
      unsigned short a, b, c;
      split3(v, a, b, c);
      u0[r] = a; u1[r] = b; u2[r] = c;
    }
    const int idx = n * 64 + ((2 * mt + (g >> 1)) ^ (n & 7)) * 8 + 4 * (g & 1);
    *(ushort4v*)(dst + idx) = u0;
    *(ushort4v*)(dst + 1024 + idx) = u1;
    *(ushort4v*)(dst + 2048 + idx) = u2;
  }
}

// raw split3 -> scratch (no bias/relu) for routing input
__device__ __forceinline__ void store4_raw(const f32x4 acc[4], unsigned short* dst, int lane) {
  const int n = lane & 15, g = lane >> 4;
  #pragma unroll
  for (int mt = 0; mt < 4; ++mt) {
    ushort4v u0, u1, u2;
    #pragma unroll
    for (int r = 0; r < 4; ++r) {
      unsigned short a, b, c;
      split3(acc[mt][r], a, b, c);
      u0[r] = a; u1[r] = b; u2[r] = c;
    }
    const int idx = n * 64 + ((2 * mt + (g >> 1)) ^ (n & 7)) * 8 + 4 * (g & 1);
    *(ushort4v*)(dst + idx) = u0;
    *(ushort4v*)(dst + 1024 + idx) = u1;
    *(ushort4v*)(dst + 2048 + idx) = u2;
  }
}

// main per-hop kernel: barrier-free per-wave pipeline. Each wave owns 16
// tokens x all 64 features; exchange via private 6KB LDS scratch (lgkmcnt
// only, no __syncthreads). 2 block barriers total (lcnt).
__global__ __launch_bounds__(TPB, 4) void k_hop(
    float* __restrict__ states, int* __restrict__ tempers, int* __restrict__ done,
    const int* __restrict__ compact, const int* __restrict__ cnt,
    const int* __restrict__ offp,
    const unsigned short* __restrict__ w1f, const float* __restrict__ b1,
    const unsigned short* __restrict__ w2f, const float* __restrict__ b2,
    const unsigned short* __restrict__ rw1f, const float* __restrict__ rb1,
    const unsigned short* __restrict__ rw2f, const float* __restrict__ rb2,
    int* __restrict__ cnt_next, HopConst hc)
{
  __shared__ unsigned short scr[4][3072];   // 24KB: 6KB private scratch per wave
  __shared__ int lcnt[TN];

  const int tid = threadIdx.x;
  const int lane = tid & 63;
  const int wid = __builtin_amdgcn_readfirstlane(tid >> 6);
  unsigned short* ws = scr[wid];
  const int bstart = blockIdx.x * TOKB;
  if (bstart >= offp[TN]) return;
  if (tid < TN) lcnt[tid] = 0;
  int tt = 0;
  #pragma unroll
  for (int i = 1; i < TN; ++i) if (bstart >= offp[i]) tt = i;
  const int t = __builtin_amdgcn_readfirstlane(tt);
  const int cntt = cnt[t];
  const int n = lane & 15, g = lane >> 4;
  const int pos = bstart + wid * 16 + n;
  const bool act = (pos - offp[t]) < cntt;
  const int tok = compact[act ? pos : offp[t]];

  // ---- stage states in-register: lane loads its token's k-slices ----
  short8v bx[3][2];
  {
    const float* sr = states + (size_t)tok * HD;
    float va[8], vb[8];
    #pragma unroll
    for (int q = 0; q < 2; ++q) {
      const float4 f0 = *(const float4*)(sr + 8 * g + q * 4);
      const float4 f1 = *(const float4*)(sr + 32 + 8 * g + q * 4);
      va[q*4] = f0.x; va[q*4+1] = f0.y; va[q*4+2] = f0.z; va[q*4+3] = f0.w;
      vb[q*4] = f1.x; vb[q*4+1] = f1.y; vb[q*4+2] = f1.z; vb[q*4+3] = f1.w;
    }
    unsigned short sa_[3][8], sb_[3][8];
    #pragma unroll
    for (int i = 0; i < 8; ++i) {
      split3(va[i], sa_[0][i], sa_[1][i], sa_[2][i]);
      split3(vb[i], sb_[0][i], sb_[1][i], sb_[2][i]);
    }
    #pragma unroll
    for (int s = 0; s < 3; ++s) {
      short8v u0, u1;
      #pragma unroll
      for (int i = 0; i < 8; ++i) { u0[i] = (short)sa_[s][i]; u1[i] = (short)sb_[s][i]; }
      bx[s][0] = u0; bx[s][1] = u1;
    }
  }
  __syncthreads();   // lcnt init visible before any sampling adds

  const f32x4 zf = {0.0f, 0.0f, 0.0f, 0.0f};
  f32x4 out4[4] = {zf, zf, zf, zf};

  #pragma unroll 1
  for (int o = 0; o < ON; ++o) {
    const int mat = t * ON + o;
    f32x4 acc[4] = {zf, zf, zf, zf};
    mfma_all4(w1f + (size_t)mat * 12288, bx, lane, acc);
    store4_rb(acc, b1 + mat * 64, ws, lane);          // h1 splits -> wave scratch
    short8v bh[3][2];
    load_bf(ws, lane, bh);                            // lgkmcnt-ordered, wave-local
    f32x4 acc2[4] = {zf, zf, zf, zf};
    mfma_all4(w2f + (size_t)mat * 12288, bh, lane, acc2);
    const float wo = hc.w[t][o];
    #pragma unroll
    for (int mt = 0; mt < 4; ++mt) {
      const float4 bv = *(const float4*)(b2 + mat * 64 + 16 * mt + 4 * g);
      const float bb[4] = {bv.x, bv.y, bv.z, bv.w};
      #pragma unroll
      for (int r = 0; r < 4; ++r)
        out4[mt][r] = fmaf(wo, fmaxf(acc2[mt][r] + bb[r], 0.0f), out4[mt][r]);
    }
  }

  // ---- states write-back (direct, 16B per store) ----
  if (act) {
    float* wr = states + (size_t)tok * HD;
    #pragma unroll
    for (int mt = 0; mt < 4; ++mt) {
      float4 v; v.x = out4[mt][0]; v.y = out4[mt][1]; v.z = out4[mt][2]; v.w = out4[mt][3];
      *(float4*)(wr + 16 * mt + 4 * g) = v;
    }
  }

  if (!hc.last_hop) {
    // ---- routing: r1 = relu(out @ rW1 + rb1) ----
    store4_raw(out4, ws, lane);
    short8v bo[3][2];
    load_bf(ws, lane, bo);
    f32x4 accr[4] = {zf, zf, zf, zf};
    mfma_all4(rw1f, bo, lane, accr);
    store4_rb(accr, rb1, ws, lane);
    short8v br[3][2];
    load_bf(ws, lane, br);

    // ---- logits = r1 @ rW2 (1 m-tile of 16 cats) ----
    f32x4 lg = zf;
    #pragma unroll
    for (int sw = 0; sw < 3; ++sw) {
      short8v a2[2];
      #pragma unroll
      for (int kc = 0; kc < 2; ++kc)
        a2[kc] = *(const short8v*)(rw2f + (size_t)(sw * 2 + kc) * 512 + lane * 8);
      #pragma unroll
      for (int sa = 0; sa < 3; ++sa) {
        if (sw + sa > 2) continue;
        #pragma unroll
        for (int kc = 0; kc < 2; ++kc)
          lg = __builtin_amdgcn_mfma_f32_16x16x32_bf16(a2[kc], br[sa][kc], lg, 0, 0, 0);
      }
    }

    // ---- gumbel-argmax: lane handles cats 4g..4g+3 of its token ----
    float best = -3.0e38f; int bc = 0;
    const unsigned jbase = (unsigned)tok * (unsigned)NCAT;
    #pragma unroll
    for (int r = 0; r < 4; ++r) {
      const int c = 4 * g + r;
      if (c < NCAT) {
        const unsigned bits = tf_bits32(hc.ck0, hc.ck1, jbase + (unsigned)c);
        const float u = __uint_as_float((bits >> 9) | 0x3f800000u) - 1.0f;
        float val = u + 1.17549435e-38f;
        val = fmaxf(val, 1.17549435e-38f);
        const float gum = -logf(-logf(val));
        const float sc = lg[r] + rb2[c] + gum;
        if (sc > best) { best = sc; bc = c; }
      }
    }
    #pragma unroll
    for (int off = 16; off <= 32; off <<= 1) {
      const float ob = __shfl_xor(best, off, 64);
      const int oc = __shfl_xor(bc, off, 64);
      if (ob > best || (ob == best && oc < bc)) { best = ob; bc = oc; }
    }
    if (g == 0 && act) {
      const int nt = bc < (TN - 1) ? bc : (TN - 1);
      tempers[tok] = nt;
      if (bc == TN) done[tok] = 1;
      else atomicAdd(&lcnt[nt], 1);
    }
    __syncthreads();
    if (tid < TN && lcnt[tid] > 0) atomicAdd(&cnt_next[tid], lcnt[tid]);
  }
}

// pred = states @ pred_W + pred_b via bf16x3 MFMA; fused err reduction
__global__ __launch_bounds__(512, 4) void k_pred(
    const float* __restrict__ states, const float* __restrict__ x,
    const unsigned short* __restrict__ pwf, const float* __restrict__ pdb,
    float* __restrict__ pred, float* __restrict__ err)
{
  __shared__ unsigned short sX[3 * 64 * 64];   // 24KB states splits
  __shared__ float sP[64 * 128];               // 32KB pred
  const int tid = threadIdx.x;
  const int lane = tid & 63;
  const int w = __builtin_amdgcn_readfirstlane(tid >> 6);
  const int mgrp = w & 3, ngrp = w >> 2;       // 4 d-quarters x 2 tok-halves
  const int bstart = blockIdx.x * 64;

  // stage states (coalesced): thread = (tok=tid>>3, c0=tid&7), 8 h each
  {
    const int tok = tid >> 3, c0 = tid & 7;
    const float* sr = states + (size_t)(bstart + tok) * HD + c0 * 8;
    float v[8];
    #pragma unroll
    for (int q = 0; q < 2; ++q) {
      const float4 f = *(const float4*)(sr + q * 4);
      v[q*4] = f.x; v[q*4+1] = f.y; v[q*4+2] = f.z; v[q*4+3] = f.w;
    }
    unsigned short sp[3][8];
    #pragma unroll
    for (int i = 0; i < 8; ++i) split3(v[i], sp[0][i], sp[1][i], sp[2][i]);
    const int chunk = c0 ^ (tok & 7);
    #pragma unroll
    for (int s = 0; s < 3; ++s) {
      ushort8v u;
      #pragma unroll
      for (int i = 0; i < 8; ++i) u[i] = sp[s][i];
      *(ushort8v*)(sX + s * 4096 + tok * 64 + chunk * 8) = u;
    }
  }
  __syncthreads();

  const f32x4 zf = {0.0f, 0.0f, 0.0f, 0.0f};
  short8v bf[3][2][2];
  #pragma unroll
  for (int s = 0; s < 3; ++s)
    #pragma unroll
    for (int nt = 0; nt < 2; ++nt)
      #pragma unroll
      for (int kc = 0; kc < 2; ++kc) {
        const int tk = (lane & 15) + 16 * (2 * ngrp + nt);
        const int chunk = (4 * kc + (lane >> 4)) ^ (tk & 7);
        bf[s][nt][kc] = *(const short8v*)(sX + s * 4096 + tk * 64 + chunk * 8);
      }

  f32x4 acc[2][2] = {{zf, zf}, {zf, zf}};
  #pragma unroll
  for (int sw = 0; sw < 3; ++sw) {
    short8v a[2][2];
    #pragma unroll
    for (int mt = 0; mt < 2; ++mt)
      #pragma unroll
      for (int kc = 0; kc < 2; ++kc)
        a[mt][kc] = *(const short8v*)(pwf +
            (size_t)((sw * 8 + (2 * mgrp + mt)) * 2 + kc) * 512 + lane * 8);
    #pragma unroll
    for (int sa = 0; sa < 3; ++sa) {
      if (sw + sa > 2) continue;
      #pragma unroll
      for (int mt = 0; mt < 2; ++mt)
        #pragma unroll
        for (int nt = 0; nt < 2; ++nt)
          #pragma unroll
          for (int kc = 0; kc < 2; ++kc)
            acc[mt][nt] = __builtin_amdgcn_mfma_f32_16x16x32_bf16(
                a[mt][kc], bf[sa][nt][kc], acc[mt][nt], 0, 0, 0);
    }
  }

  // D + bias -> swizzled f32 LDS
  #pragma unroll
  for (int mt = 0; mt < 2; ++mt) {
    const int mt2 = 2 * mgrp + mt;
    const int d0 = 16 * mt2 + 4 * (lane >> 4);
    const float4 bv = *(const float4*)(pdb + d0);
    const float bb[4] = {bv.x, bv.y, bv.z, bv.w};
    #pragma unroll
    for (int nt = 0; nt < 2; ++nt) {
      const int tok = (lane & 15) + 16 * (2 * ngrp + nt);
      f32x4 vv;
      #pragma unroll
      for (int r = 0; r < 4; ++r) vv[r] = acc[mt][nt][r] + bb[r];
      const int chunk = (d0 >> 2) ^ (tok & 7);
      *(f32x4*)(sP + tok * 128 + chunk * 4) = vv;
    }
  }
  __syncthreads();

  // coalesced pred write + fused err
  {
    const int tok = tid >> 3, c0 = tid & 7;
    const int n = bstart + tok;
    const float* xr = x + (size_t)n * DIN;
    float* pr = pred + (size_t)n * DIN;
    float s = 0.0f;
    #pragma unroll
    for (int q = 0; q < 4; ++q) {
      const int c = c0 + 8 * q;
      const int cs = c ^ (tok & 7);
      const f32x4 pv = *(const f32x4*)(sP + tok * 128 + cs * 4);
      const float4 xv = *(const float4*)(xr + c * 4);
      float4 ov; ov.x = pv[0]; ov.y = pv[1]; ov.z = pv[2]; ov.w = pv[3];
      *(float4*)(pr + c * 4) = ov;
      const float e0 = pv[0] - xv.x, e1 = pv[1] - xv.y, e2 = pv[2] - xv.z, e3 = pv[3] - xv.w;
      s += e0 * e0 + e1 * e1 + e2 * e2 + e3 * e3;
    }
    s += __shfl_xor(s, 1, 64);
    s += __shfl_xor(s, 2, 64);
    s += __shfl_xor(s, 4, 64);
    if (c0 == 0) err[n] = s * (1.0f / 128.0f);
  }
}

// ---- host-side RNG constant derivation ----
static float host_erfinv(float xf) {
  double x = xf;
  double w = -log1p(-x * x);
  double p;
  if (w < 5.0) {
    w -= 2.5;
    p = 2.81022636e-08;          p = 3.43273939e-07 + p * w;
    p = -3.5233877e-06 + p * w;  p = -4.39150654e-06 + p * w;
    p = 0.00021858087 + p * w;   p = -0.00125372503 + p * w;
    p = -0.00417768164 + p * w;  p = 0.246640727 + p * w;
    p = 1.50140941 + p * w;
  } else {
    w = sqrt(w) - 3.0;
    p = -0.000200214257;         p = 0.000100950558 + p * w;
    p = 0.00134934322 + p * w;   p = -0.00367342844 + p * w;
    p = 0.00573950773 + p * w;   p = -0.0076224613 + p * w;
    p = 0.00943887047 + p * w;   p = 1.00167406 + p * w;
    p = 2.83297682 + p * w;
  }
  return (float)(p * x);
}

static void build_hops(HopConst* hcs) {
  const float lo = nextafterf(-1.0f, 0.0f);
  const unsigned rk0 = 0u, rk1 = 42u;
  for (int hop = 0; hop < NHOPS; ++hop) {
    unsigned hk0, hk1;
    tf2x32(rk0, rk1, 0u, (unsigned)hop, hk0, hk1);
    for (int t = 0; t < TN; ++t) {
      unsigned tk0, tk1;
      tf2x32(hk0, hk1, 0u, (unsigned)t, tk0, tk1);
      double nrm[3];
      for (int i = 0; i < 3; ++i) {
        const unsigned bits = tf_bits32(tk0, tk1, (unsigned)i);
        unsigned ub = (bits >> 9) | 0x3f800000u;
        float f; memcpy(&f, &ub, 4);
        const float u01 = f - 1.0f;
        float val = u01 * 2.0f + lo;
        if (val < lo) val = lo;
        const float ef = host_erfinv(val);
        nrm[i] = (double)(1.41421356f * ef);
      }
      const double m = fmax(nrm[0], fmax(nrm[1], nrm[2]));
      const double e0 = exp(nrm[0] - m), e1 = exp(nrm[1] - m), e2 = exp(nrm[2] - m);
      const double s = e0 + e1 + e2;
      hcs[hop].w[t][0] = (float)(e0 / s);
      hcs[hop].w[t][1] = (float)(e1 / s);
      hcs[hop].w[t][2] = (float)(e2 / s);
    }
    unsigned ck0, ck1;
    tf2x32(hk0, hk1, 0u, 10000u, ck0, ck1);
    hcs[hop].ck0 = ck0; hcs[hop].ck1 = ck1;
    hcs[hop].last_hop = (hop == NHOPS - 1) ? 1 : 0;
  }
}

extern "C" void kernel_launch(void* const* d_in, const int* in_sizes, int n_in,
                              void* d_out, int out_size, void* d_ws, size_t ws_size,
                              hipStream_t stream) {
  (void)in_sizes; (void)n_in; (void)out_size; (void)ws_size;
  const float* x    = (const float*)d_in[0];
  const float* pW   = (const float*)d_in[1];
  const float* pb   = (const float*)d_in[2];
  const float* W1   = (const float*)d_in[3];
  const float* b1   = (const float*)d_in[4];
  const float* W2   = (const float*)d_in[5];
  const float* b2   = (const float*)d_in[6];
  const float* rW1  = (const float*)d_in[7];
  const float* rb1  = (const float*)d_in[8];
  const float* rW2  = (const float*)d_in[9];
  const float* rb2  = (const float*)d_in[10];
  const float* pdW  = (const float*)d_in[11];
  const float* pdb  = (const float*)d_in[12];
  const int*   itmp = (const int*)d_in[13];

  // ws: [meta 1KB][tempers N][done N][compact N+TN*TOKB][states N*64 f32]
  //     [w1f][w2f][rw1f][rw2f][pjf][pwf] (u16 frag arrays)
  int* meta    = (int*)d_ws;
  int* tempers = (int*)((char*)d_ws + 1024);
  int* done    = tempers + N_TOK;
  int* compact = done + N_TOK;
  float* states = (float*)(compact + N_TOK + TN * TOKB);
  unsigned short* w1f  = (unsigned short*)(states + (size_t)N_TOK * HD);
  unsigned short* w2f  = w1f + (size_t)TN * ON * 12288;
  unsigned short* rw1f = w2f + (size_t)TN * ON * 12288;
  unsigned short* rw2f = rw1f + 12288;
  unsigned short* pjf  = rw2f + 3072;
  unsigned short* pwf  = pjf + 24576;

  HopConst hcs[NHOPS];
  build_hops(hcs);

  hipMemsetAsync(meta, 0, 160 * sizeof(int), stream);
  k_wprep<<<83, TPB, 0, stream>>>(W1, W2, rW1, rW2, pW, pdW,
                                  w1f, w2f, rw1f, rw2f, pjf, pwf);
  k_init<<<N_TOK / 64, 512, 0, stream>>>(x, pjf, pb, itmp, states, tempers, done, meta);
  for (int h = 0; h < NHOPS; ++h) {
    int* cnt_h = meta + h * TN;
    int* cnt_n = meta + (h + 1) * TN;
    int* cur_h = meta + 60 + h * TN;
    int* off_h = meta + 108 + h * (TN + 1);
    k_prefix<<<1, 64, 0, stream>>>(cnt_h, off_h);
    k_scatter<<<N_TOK / TPB, TPB, 0, stream>>>(tempers, done, off_h, cur_h, compact);
    k_hop<<<N_TOK / TOKB + TN, TPB, 0, stream>>>(states, tempers, done, compact, cnt_h, off_h,
        w1f, b1, w2f, b2, rw1f, rb1, rw2f, rb2, cnt_n, hcs[h]);
  }
  float* pred = (float*)d_out;
  float* errp = pred + (size_t)N_TOK * DIN;
  k_pred<<<N_TOK / 64, 512, 0, stream>>>(states, x, pwf, pdb, pred, errp);
}